// Round 8
// baseline (906.242 us; speedup 1.0000x reference)
//
#include <hip/hip_runtime.h>
#include <hip/hip_bf16.h>
#include <cstdint>
#include <cstddef>

#define DNODE 64
#define HDIM 256
#define NLAYERS 3
#define NPART 8

typedef __attribute__((ext_vector_type(8))) short bf16x8;
typedef __attribute__((ext_vector_type(4))) float f32x4;

__device__ __forceinline__ ushort f2bf(float f) {
    __hip_bfloat16 b = __float2bfloat16(f);
    return *(ushort*)&b;
}
__device__ __forceinline__ float bf2f(ushort u) {
    return __uint_as_float((uint32_t)u << 16);
}
__device__ __forceinline__ unsigned char f2fp8(float f) {
    int p = __builtin_amdgcn_cvt_pk_fp8_f32(f, f, 0, false);
    return (unsigned char)(p & 0xFF);
}

// ---------------------------------------------------------------------------
// k_pre: deg histogram + x->bf16 convert + weight transposes, one launch
// ---------------------------------------------------------------------------
__global__ __launch_bounds__(256) void k_pre(const int* __restrict__ edst, int* __restrict__ deg, int E, int degB,
                                             const float* __restrict__ x, ushort* __restrict__ xb, int n4, int xcB,
                                             const float* __restrict__ w_node, ushort* __restrict__ wnt,
                                             const float* __restrict__ w_gnn, ushort* __restrict__ wgt) {
    int b = blockIdx.x, tid = threadIdx.x;
    if (b < degB) {
        int e = b * 256 + tid;
        if (e < E) atomicAdd(&deg[edst[e]], 1);
    } else if (b < degB + xcB) {
        int i = (b - degB) * 256 + tid;
        if (i < n4) {
            float4 v = *(const float4*)&x[(size_t)i * 4];
            ushort4 o;
            o.x = f2bf(v.x); o.y = f2bf(v.y); o.z = f2bf(v.z); o.w = f2bf(v.w);
            *(ushort4*)&xb[(size_t)i * 4] = o;
        }
    } else {
        int wb = b - degB - xcB;
        int n = tid;
        if (wb < DNODE / 16) {
            int k0 = wb * 16;
#pragma unroll
            for (int i = 0; i < 16; i++)
                wnt[(size_t)n * DNODE + k0 + i] = f2bf(w_node[(size_t)(k0 + i) * HDIM + n]);
        } else {
            wb -= DNODE / 16;
            int l = wb >> 4, k0 = (wb & 15) * 16;
            const float* s = w_gnn + (size_t)l * HDIM * HDIM;
            ushort* d = wgt + (size_t)l * HDIM * HDIM;
#pragma unroll
            for (int i = 0; i < 16; i++)
                d[(size_t)n * HDIM + k0 + i] = f2bf(s[(size_t)(k0 + i) * HDIM + n]);
        }
    }
}

// ---------------------------------------------------------------------------
// Scan chain (unchanged, proven)
// ---------------------------------------------------------------------------
__global__ __launch_bounds__(256) void k_scan_partial(const int* __restrict__ deg, int* __restrict__ bsum, int n) {
    __shared__ int sd[256];
    int tid = threadIdx.x;
    int base = blockIdx.x * 2048 + tid * 8;
    int s = 0;
#pragma unroll
    for (int j = 0; j < 8; j++) {
        int idx = base + j;
        if (idx < n) s += deg[idx];
    }
    sd[tid] = s;
    __syncthreads();
    for (int off = 128; off > 0; off >>= 1) {
        if (tid < off) sd[tid] += sd[tid + off];
        __syncthreads();
    }
    if (tid == 0) bsum[blockIdx.x] = sd[0];
}

__global__ void k_scan_bsum(int* bsum, int nb) {
    if (threadIdx.x == 0 && blockIdx.x == 0) {
        int run = 0;
        for (int i = 0; i < nb; i++) { int v = bsum[i]; bsum[i] = run; run += v; }
    }
}

__global__ __launch_bounds__(256) void k_scan_final(const int* __restrict__ deg, const int* __restrict__ bsum,
                                                    int* __restrict__ row_ptr, int* __restrict__ cursor,
                                                    float* __restrict__ inv_den, int n, int Etot) {
    __shared__ int tsum[256];
    int tid = threadIdx.x;
    int base = blockIdx.x * 2048 + tid * 8;
    int loc[8], dv[8];
    int s = 0;
#pragma unroll
    for (int j = 0; j < 8; j++) {
        int idx = base + j;
        int v = (idx < n) ? deg[idx] : 0;
        dv[j] = v;
        loc[j] = s;
        s += v;
    }
    tsum[tid] = s;
    __syncthreads();
    for (int off = 1; off < 256; off <<= 1) {
        int t = (tid >= off) ? tsum[tid - off] : 0;
        __syncthreads();
        tsum[tid] += t;
        __syncthreads();
    }
    int off0 = bsum[blockIdx.x] + (tid ? tsum[tid - 1] : 0);
#pragma unroll
    for (int j = 0; j < 8; j++) {
        int idx = base + j;
        if (idx < n) {
            int rp = off0 + loc[j];
            row_ptr[idx] = rp;
            cursor[idx] = rp;
            int d = dv[j];
            inv_den[idx] = 1.0f / (float)(d > 0 ? d : 1);
        }
    }
    if (blockIdx.x == 0 && tid == 0) row_ptr[n] = Etot;
}

// ---------------------------------------------------------------------------
// k_fill_part: XCD-partitioned CSR fill (round-7 proven)
// ---------------------------------------------------------------------------
__global__ __launch_bounds__(256) void k_fill_part(const int* __restrict__ esrc, const int* __restrict__ edst,
                                                   int* __restrict__ cursor, int* __restrict__ colx,
                                                   int E, int npp, int nslices) {
    int part = blockIdx.x & (NPART - 1);
    int slice = blockIdx.x / NPART;
    int lo = part * npp;
    int hi = lo + npp;
    int stride = nslices * 256;
    for (int e = slice * 256 + (int)threadIdx.x; e < E; e += stride) {
        int d = edst[e];
        if (d >= lo && d < hi) {
            int p = atomicAdd(&cursor[d], 1);
            colx[p] = esrc[e];
        }
    }
}

// ---------------------------------------------------------------------------
// Aggregation (round-5 proven): fp8 gather, one node per 16-lane group,
// 4-deep edge unroll, fp32 acc, bf16 msg out.
// ---------------------------------------------------------------------------
__device__ __forceinline__ void acc_fp8x16(uint4 v, float* acc) {
    uint32_t d[4] = {v.x, v.y, v.z, v.w};
#pragma unroll
    for (int i = 0; i < 4; i++) {
        auto lo = __builtin_amdgcn_cvt_pk_f32_fp8(d[i], false);
        auto hi = __builtin_amdgcn_cvt_pk_f32_fp8(d[i], true);
        acc[i * 4 + 0] += lo[0];
        acc[i * 4 + 1] += lo[1];
        acc[i * 4 + 2] += hi[0];
        acc[i * 4 + 3] += hi[1];
    }
}

__global__ __launch_bounds__(256) void k_aggregate_fp8(const unsigned char* __restrict__ h8,
                                                       const int* __restrict__ row_ptr,
                                                       const int* __restrict__ colx,
                                                       const float* __restrict__ inv_den,
                                                       ushort* __restrict__ msgb, int N) {
    int tid = threadIdx.x;
    int node = blockIdx.x * 16 + (tid >> 4);
    if (node >= N) return;
    int f = tid & 15;
    int gbase = tid & 48;
    const unsigned char* hp = h8 + (size_t)f * 16;

    int s = row_ptr[node], e = row_ptr[node + 1];
    float acc[16] = {};

    for (int base = s; base < e; base += 16) {
        int rem = e - base;
        int cnt = rem > 16 ? 16 : rem;
        int cv = (f < cnt) ? colx[base + f] : 0;
        int t = 0;
        for (; t + 3 < cnt; t += 4) {
            int c0 = __shfl(cv, gbase + t);
            int c1 = __shfl(cv, gbase + t + 1);
            int c2 = __shfl(cv, gbase + t + 2);
            int c3 = __shfl(cv, gbase + t + 3);
            uint4 v0 = *(const uint4*)&hp[(size_t)c0 * HDIM];
            uint4 v1 = *(const uint4*)&hp[(size_t)c1 * HDIM];
            uint4 v2 = *(const uint4*)&hp[(size_t)c2 * HDIM];
            uint4 v3 = *(const uint4*)&hp[(size_t)c3 * HDIM];
            acc_fp8x16(v0, acc);
            acc_fp8x16(v1, acc);
            acc_fp8x16(v2, acc);
            acc_fp8x16(v3, acc);
        }
        for (; t < cnt; t++) {
            int c0 = __shfl(cv, gbase + t);
            uint4 v0 = *(const uint4*)&hp[(size_t)c0 * HDIM];
            acc_fp8x16(v0, acc);
        }
    }

    float inv = inv_den[node];
    ushort o[16];
#pragma unroll
    for (int k = 0; k < 16; k++) o[k] = f2bf(acc[k] * inv);
    ushort* mp = &msgb[(size_t)node * HDIM + f * 16];
    *(uint4*)&mp[0] = *(uint4*)&o[0];
    *(uint4*)&mp[8] = *(uint4*)&o[8];
}

// ---------------------------------------------------------------------------
// k_gemm_direct: barrier-free, LDS-free MFMA GEMM.
// grid = ceil(M/64) blocks x 4 waves; wave owns 16 rows x all 256 cols.
// A/B fragments loaded directly from global (A streamed once, full 64B
// lines; B is 128KB, L2/L1-resident). acc = 16 x f32x4 (64 VGPR).
// LAST: no H writes; per-block LDS column-sum -> atomicAdd into g.
// ---------------------------------------------------------------------------
template <int K, bool ADD, bool RELU, bool W8, bool LAST>
__global__ __launch_bounds__(256) void k_gemm_direct(const ushort* __restrict__ A,
                                                     const ushort* __restrict__ Bt,
                                                     const float* __restrict__ bias,
                                                     ushort* __restrict__ H,
                                                     unsigned char* __restrict__ H8,
                                                     float* __restrict__ g,
                                                     int M) {
    __shared__ float cols[256];
    int tid = threadIdx.x;
    int w = tid >> 6, l = tid & 63;
    int rw0 = blockIdx.x * 64 + w * 16;
    int fr = l & 15, fk = (l >> 4) * 8;
    int arow = rw0 + fr;
    bool aval = arow < M;
    const ushort* ap = &A[(size_t)arow * K + fk];

    f32x4 acc[16];
#pragma unroll
    for (int ni = 0; ni < 16; ni++) acc[ni] = (f32x4){0.f, 0.f, 0.f, 0.f};

#pragma unroll 2
    for (int kk = 0; kk < K / 32; kk++) {
        bf16x8 av = {0, 0, 0, 0, 0, 0, 0, 0};
        if (aval) av = *(const bf16x8*)&ap[kk * 32];
        bf16x8 bv[16];
#pragma unroll
        for (int ni = 0; ni < 16; ni++)
            bv[ni] = *(const bf16x8*)&Bt[(size_t)(ni * 16 + fr) * K + kk * 32 + fk];
#pragma unroll
        for (int ni = 0; ni < 16; ni++)
            acc[ni] = __builtin_amdgcn_mfma_f32_16x16x32_bf16(av, bv[ni], acc[ni], 0, 0, 0);
    }

    if (LAST) {
        cols[tid] = 0.f;
        __syncthreads();
    }
#pragma unroll
    for (int ni = 0; ni < 16; ni++) {
        int gcol = ni * 16 + fr;
        float bb = bias[gcol];
        float csum = 0.f;
#pragma unroll
        for (int j = 0; j < 4; j++) {
            int grow = rw0 + (l >> 4) * 4 + j;
            if (grow >= M) continue;
            size_t idx = (size_t)grow * HDIM + gcol;
            float v = acc[ni][j] + bb;
            if (ADD) v += bf2f(H[idx]);
            if (RELU) v = fmaxf(v, 0.f);
            if (LAST) {
                csum += v;
            } else {
                H[idx] = f2bf(v);
                if (W8) H8[idx] = f2fp8(v);
            }
        }
        if (LAST) atomicAdd(&cols[gcol], csum);
    }
    if (LAST) {
        __syncthreads();
        atomicAdd(&g[tid], cols[tid]);
    }
}

// ---------------------------------------------------------------------------
// Tiny MLP head (fp32)
// ---------------------------------------------------------------------------
__global__ __launch_bounds__(256) void k_mlp(const float* __restrict__ g, const float* __restrict__ w1,
                                             const float* __restrict__ b1, const float* __restrict__ w2,
                                             const float* __restrict__ b2, float* __restrict__ out, float invN) {
    __shared__ float gs[256];
    __shared__ float ts[256];
    int f = threadIdx.x;
    gs[f] = g[f] * invN;
    __syncthreads();
    float a = b1[f];
    for (int k = 0; k < 256; k++) a = fmaf(gs[k], w1[k * 256 + f], a);
    ts[f] = fmaxf(a, 0.f);
    __syncthreads();
    float o = b2[f];
    for (int k = 0; k < 256; k++) o = fmaf(ts[k], w2[k * 256 + f], o);
    out[f] = o;
}

// ---------------------------------------------------------------------------
extern "C" void kernel_launch(void* const* d_in, const int* in_sizes, int n_in,
                              void* d_out, int out_size, void* d_ws, size_t ws_size,
                              hipStream_t stream) {
    const float* x      = (const float*)d_in[0];
    const int*   src    = (const int*)d_in[1];
    const int*   dst    = (const int*)d_in[2];
    const float* w_node = (const float*)d_in[3];
    const float* b_node = (const float*)d_in[4];
    const float* w_gnn  = (const float*)d_in[5];
    const float* b_gnn  = (const float*)d_in[6];
    const float* w_p1   = (const float*)d_in[7];
    const float* b_p1   = (const float*)d_in[8];
    const float* w_p2   = (const float*)d_in[9];
    const float* b_p2   = (const float*)d_in[10];
    float* out = (float*)d_out;

    const int N = in_sizes[0] / DNODE;  // 100000
    const int E = in_sizes[1];          // 1600000

    // workspace layout (~155 MB)
    char* w = (char*)d_ws;
    ushort* hb     = (ushort*)w;            w += (size_t)N * HDIM * 2;
    ushort* msgb   = (ushort*)w;            w += (size_t)N * HDIM * 2;
    unsigned char* h8 = (unsigned char*)w;  w += (size_t)N * HDIM;
    ushort* xb     = (ushort*)w;            w += (size_t)N * DNODE * 2;
    ushort* wnt    = (ushort*)w;            w += (size_t)HDIM * DNODE * 2;
    ushort* wgt    = (ushort*)w;            w += (size_t)NLAYERS * HDIM * HDIM * 2;
    int*   deg     = (int*)w;               w += (size_t)N * 4;
    int*   row_ptr = (int*)w;               w += (size_t)(N + 1) * 4;
    int*   cursor  = (int*)w;               w += (size_t)N * 4;
    int*   colx    = (int*)w;               w += (size_t)E * 4;
    float* inv_den = (float*)w;             w += (size_t)N * 4;
    float* g       = (float*)w;             w += 256 * 4;
    int*   bsum    = (int*)w;               w += 256 * 4;
    (void)ws_size; (void)n_in; (void)out_size;

    hipMemsetAsync(deg, 0, (size_t)N * 4, stream);
    hipMemsetAsync(g, 0, 256 * 4, stream);

    // deg histogram + converts (one launch)
    int degB = (E + 255) / 256;
    int n4 = N * DNODE / 4;
    int xcB = (n4 + 255) / 256;
    int wcB = DNODE / 16 + NLAYERS * (HDIM / 16);
    k_pre<<<degB + xcB + wcB, 256, 0, stream>>>(dst, deg, E, degB, x, xb, n4, xcB,
                                                w_node, wnt, w_gnn, wgt);

    // scan chain
    int nb = (N + 2047) / 2048;
    k_scan_partial<<<nb, 256, 0, stream>>>(deg, bsum, N);
    k_scan_bsum<<<1, 64, 0, stream>>>(bsum, nb);
    k_scan_final<<<nb, 256, 0, stream>>>(deg, bsum, row_ptr, cursor, inv_den, N, E);

    // CSR fill — XCD-partitioned for colx L2 residency
    int npp = (N + NPART - 1) / NPART;
    int nslices = 256;
    k_fill_part<<<NPART * nslices, 256, 0, stream>>>(src, dst, cursor, colx, E, npp, nslices);

    // node projection -> hb + h8
    int nblk = (N + 63) / 64;
    k_gemm_direct<DNODE, false, false, true, false><<<nblk, 256, 0, stream>>>(
        xb, wnt, b_node, hb, h8, nullptr, N);

    // GNN layers
    int nagg = (N + 15) / 16;
    for (int l = 0; l < NLAYERS; l++) {
        k_aggregate_fp8<<<nagg, 256, 0, stream>>>(h8, row_ptr, colx, inv_den, msgb, N);
        const ushort* Bt = wgt + (size_t)l * HDIM * HDIM;
        const float* bg = b_gnn + (size_t)l * HDIM;
        if (l < NLAYERS - 1)
            k_gemm_direct<HDIM, true, true, true, false><<<nblk, 256, 0, stream>>>(
                msgb, Bt, bg, hb, h8, nullptr, N);
        else
            k_gemm_direct<HDIM, true, true, false, true><<<nblk, 256, 0, stream>>>(
                msgb, Bt, bg, hb, nullptr, g, N);
    }

    k_mlp<<<1, 256, 0, stream>>>(g, w_p1, b_p1, w_p2, b_p2, out, 1.0f / (float)N);
}

// Round 9
// 712.744 us; speedup vs baseline: 1.2715x; 1.2715x over previous
//
#include <hip/hip_runtime.h>
#include <hip/hip_bf16.h>
#include <cstdint>
#include <cstddef>

#define DNODE 64
#define HDIM 256
#define NLAYERS 3
#define NPART 8
#define NSLICE 8

typedef __attribute__((ext_vector_type(8))) short bf16x8;
typedef __attribute__((ext_vector_type(4))) float f32x4;

__device__ __forceinline__ ushort f2bf(float f) {
    __hip_bfloat16 b = __float2bfloat16(f);
    return *(ushort*)&b;
}
__device__ __forceinline__ float bf2f(ushort u) {
    return __uint_as_float((uint32_t)u << 16);
}
__device__ __forceinline__ unsigned char f2fp8(float f) {
    int p = __builtin_amdgcn_cvt_pk_fp8_f32(f, f, 0, false);
    return (unsigned char)(p & 0xFF);
}

// ---------------------------------------------------------------------------
// k_pre: deg histogram + x->bf16 convert + weight transposes, one launch
// ---------------------------------------------------------------------------
__global__ __launch_bounds__(256) void k_pre(const int* __restrict__ edst, int* __restrict__ deg, int E, int degB,
                                             const float* __restrict__ x, ushort* __restrict__ xb, int n4, int xcB,
                                             const float* __restrict__ w_node, ushort* __restrict__ wnt,
                                             const float* __restrict__ w_gnn, ushort* __restrict__ wgt) {
    int b = blockIdx.x, tid = threadIdx.x;
    if (b < degB) {
        int e = b * 256 + tid;
        if (e < E) atomicAdd(&deg[edst[e]], 1);
    } else if (b < degB + xcB) {
        int i = (b - degB) * 256 + tid;
        if (i < n4) {
            float4 v = *(const float4*)&x[(size_t)i * 4];
            ushort4 o;
            o.x = f2bf(v.x); o.y = f2bf(v.y); o.z = f2bf(v.z); o.w = f2bf(v.w);
            *(ushort4*)&xb[(size_t)i * 4] = o;
        }
    } else {
        int wb = b - degB - xcB;
        int n = tid;
        if (wb < DNODE / 16) {
            int k0 = wb * 16;
#pragma unroll
            for (int i = 0; i < 16; i++)
                wnt[(size_t)n * DNODE + k0 + i] = f2bf(w_node[(size_t)(k0 + i) * HDIM + n]);
        } else {
            wb -= DNODE / 16;
            int l = wb >> 4, k0 = (wb & 15) * 16;
            const float* s = w_gnn + (size_t)l * HDIM * HDIM;
            ushort* d = wgt + (size_t)l * HDIM * HDIM;
#pragma unroll
            for (int i = 0; i < 16; i++)
                d[(size_t)n * HDIM + k0 + i] = f2bf(s[(size_t)(k0 + i) * HDIM + n]);
        }
    }
}

// ---------------------------------------------------------------------------
// Scan chain (unchanged, proven)
// ---------------------------------------------------------------------------
__global__ __launch_bounds__(256) void k_scan_partial(const int* __restrict__ deg, int* __restrict__ bsum, int n) {
    __shared__ int sd[256];
    int tid = threadIdx.x;
    int base = blockIdx.x * 2048 + tid * 8;
    int s = 0;
#pragma unroll
    for (int j = 0; j < 8; j++) {
        int idx = base + j;
        if (idx < n) s += deg[idx];
    }
    sd[tid] = s;
    __syncthreads();
    for (int off = 128; off > 0; off >>= 1) {
        if (tid < off) sd[tid] += sd[tid + off];
        __syncthreads();
    }
    if (tid == 0) bsum[blockIdx.x] = sd[0];
}

__global__ void k_scan_bsum(int* bsum, int nb) {
    if (threadIdx.x == 0 && blockIdx.x == 0) {
        int run = 0;
        for (int i = 0; i < nb; i++) { int v = bsum[i]; bsum[i] = run; run += v; }
    }
}

__global__ __launch_bounds__(256) void k_scan_final(const int* __restrict__ deg, const int* __restrict__ bsum,
                                                    int* __restrict__ row_ptr, int* __restrict__ cursor,
                                                    float* __restrict__ inv_den, int n, int Etot) {
    __shared__ int tsum[256];
    int tid = threadIdx.x;
    int base = blockIdx.x * 2048 + tid * 8;
    int loc[8], dv[8];
    int s = 0;
#pragma unroll
    for (int j = 0; j < 8; j++) {
        int idx = base + j;
        int v = (idx < n) ? deg[idx] : 0;
        dv[j] = v;
        loc[j] = s;
        s += v;
    }
    tsum[tid] = s;
    __syncthreads();
    for (int off = 1; off < 256; off <<= 1) {
        int t = (tid >= off) ? tsum[tid - off] : 0;
        __syncthreads();
        tsum[tid] += t;
        __syncthreads();
    }
    int off0 = bsum[blockIdx.x] + (tid ? tsum[tid - 1] : 0);
#pragma unroll
    for (int j = 0; j < 8; j++) {
        int idx = base + j;
        if (idx < n) {
            int rp = off0 + loc[j];
            row_ptr[idx] = rp;
            cursor[idx] = rp;
            int d = dv[j];
            inv_den[idx] = 1.0f / (float)(d > 0 ? d : 1);
        }
    }
    if (blockIdx.x == 0 && tid == 0) row_ptr[n] = Etot;
}

// ---------------------------------------------------------------------------
// k_fill_part: XCD-partitioned CSR fill (round-7 proven)
// ---------------------------------------------------------------------------
__global__ __launch_bounds__(256) void k_fill_part(const int* __restrict__ esrc, const int* __restrict__ edst,
                                                   int* __restrict__ cursor, int* __restrict__ colx,
                                                   int E, int npp, int nslices) {
    int part = blockIdx.x & (NPART - 1);
    int slice = blockIdx.x / NPART;
    int lo = part * npp;
    int hi = lo + npp;
    int stride = nslices * 256;
    for (int e = slice * 256 + (int)threadIdx.x; e < E; e += stride) {
        int d = edst[e];
        if (d >= lo && d < hi) {
            int p = atomicAdd(&cursor[d], 1);
            colx[p] = esrc[e];
        }
    }
}

// ---------------------------------------------------------------------------
// k_agg_slice: XCD-local fp8 gather. h8s layout [8][N][32] (feature-sliced,
// 3.2MB/slice fits one XCD L2). slice = blockIdx&7 round-robins onto XCD s,
// so each XCD's random gather hits its own L2-resident slice. 4 lanes/node,
// 16 nodes/wave, shfl-broadcast col + 4-deep unrolled 8B loads (proven loop).
// ---------------------------------------------------------------------------
__device__ __forceinline__ void acc_fp8x8(uint2 v, float* acc) {
    uint32_t d[2] = {v.x, v.y};
#pragma unroll
    for (int i = 0; i < 2; i++) {
        auto lo = __builtin_amdgcn_cvt_pk_f32_fp8(d[i], false);
        auto hi = __builtin_amdgcn_cvt_pk_f32_fp8(d[i], true);
        acc[i * 4 + 0] += lo[0];
        acc[i * 4 + 1] += lo[1];
        acc[i * 4 + 2] += hi[0];
        acc[i * 4 + 3] += hi[1];
    }
}

__global__ __launch_bounds__(256) void k_agg_slice(const unsigned char* __restrict__ h8s,
                                                   const int* __restrict__ row_ptr,
                                                   const int* __restrict__ colx,
                                                   const float* __restrict__ inv_den,
                                                   ushort* __restrict__ msgb, int N) {
    int s = blockIdx.x & (NSLICE - 1);
    int blk = blockIdx.x >> 3;
    int tid = threadIdx.x;
    int node = blk * 64 + (tid >> 2);
    if (node >= N) return;
    int f = tid & 3;
    int gbase = (tid & 63) & 60;  // 4-lane group base within wave
    const unsigned char* hp = h8s + (size_t)s * N * 32 + f * 8;

    int st = row_ptr[node], en = row_ptr[node + 1];
    float acc[8] = {};

    for (int base = st; base < en; base += 4) {
        int rem = en - base;
        int cnt = rem > 4 ? 4 : rem;
        int cv = (f < cnt) ? colx[base + f] : 0;
        if (cnt == 4) {
            int c0 = __shfl(cv, gbase + 0);
            int c1 = __shfl(cv, gbase + 1);
            int c2 = __shfl(cv, gbase + 2);
            int c3 = __shfl(cv, gbase + 3);
            uint2 v0 = *(const uint2*)&hp[(size_t)c0 * 32];
            uint2 v1 = *(const uint2*)&hp[(size_t)c1 * 32];
            uint2 v2 = *(const uint2*)&hp[(size_t)c2 * 32];
            uint2 v3 = *(const uint2*)&hp[(size_t)c3 * 32];
            acc_fp8x8(v0, acc);
            acc_fp8x8(v1, acc);
            acc_fp8x8(v2, acc);
            acc_fp8x8(v3, acc);
        } else {
            for (int t = 0; t < cnt; t++) {
                int c0 = __shfl(cv, gbase + t);
                uint2 v0 = *(const uint2*)&hp[(size_t)c0 * 32];
                acc_fp8x8(v0, acc);
            }
        }
    }

    float inv = inv_den[node];
    ushort o[8];
#pragma unroll
    for (int k = 0; k < 8; k++) o[k] = f2bf(acc[k] * inv);
    ushort* mp = &msgb[(size_t)node * HDIM + s * 32 + f * 8];
    *(uint4*)mp = *(uint4*)o;
}

// ---------------------------------------------------------------------------
// bf16 MFMA GEMM (round-7 proven): H = act((ADD?H:0) + A @ Bt^T + bias)
// W8: also write fp8 mirror to SLICED h8s[8][N][32].
// ---------------------------------------------------------------------------
template <bool ADD, bool RELU, bool W8>
__global__ __launch_bounds__(256) void k_gemm_mfma(const ushort* __restrict__ A,
                                                   const ushort* __restrict__ Bt,
                                                   const float* __restrict__ bias,
                                                   ushort* __restrict__ H,
                                                   unsigned char* __restrict__ H8s,
                                                   int M, int K) {
    __shared__ ushort As[64][40];
    __shared__ ushort Bs[64][40];
    int tid = threadIdx.x;
    int w = tid >> 6, l = tid & 63;
    int row0 = blockIdx.y * 64, col0 = blockIdx.x * 64;
    int sr = tid >> 2, sc = (tid & 3) * 8;
    int wm = (w >> 1) * 32, wn = (w & 1) * 32;
    int fr = l & 15, fk = (l >> 4) * 8;
    f32x4 acc[2][2] = {};

    for (int k0 = 0; k0 < K; k0 += 32) {
        bf16x8 av = {0, 0, 0, 0, 0, 0, 0, 0};
        int gr = row0 + sr;
        if (gr < M) av = *(const bf16x8*)&A[(size_t)gr * K + k0 + sc];
        *(bf16x8*)&As[sr][sc] = av;
        *(bf16x8*)&Bs[sr][sc] = *(const bf16x8*)&Bt[(size_t)(col0 + sr) * K + k0 + sc];
        __syncthreads();
        bf16x8 af[2], bf[2];
#pragma unroll
        for (int mi = 0; mi < 2; mi++) af[mi] = *(const bf16x8*)&As[wm + mi * 16 + fr][fk];
#pragma unroll
        for (int ni = 0; ni < 2; ni++) bf[ni] = *(const bf16x8*)&Bs[wn + ni * 16 + fr][fk];
#pragma unroll
        for (int mi = 0; mi < 2; mi++)
#pragma unroll
            for (int ni = 0; ni < 2; ni++)
                acc[mi][ni] = __builtin_amdgcn_mfma_f32_16x16x32_bf16(af[mi], bf[ni], acc[mi][ni], 0, 0, 0);
        __syncthreads();
    }

#pragma unroll
    for (int ni = 0; ni < 2; ni++) {
        int gcol = col0 + wn + ni * 16 + fr;
        float bb = bias[gcol];
        int sl = gcol >> 5, so = gcol & 31;
#pragma unroll
        for (int mi = 0; mi < 2; mi++) {
#pragma unroll
            for (int j = 0; j < 4; j++) {
                int grow = row0 + wm + mi * 16 + (l >> 4) * 4 + j;
                if (grow >= M) continue;
                size_t idx = (size_t)grow * HDIM + gcol;
                float v = acc[mi][ni][j] + bb;
                if (ADD) v += bf2f(H[idx]);
                if (RELU) v = fmaxf(v, 0.f);
                H[idx] = f2bf(v);
                if (W8) H8s[((size_t)sl * M + grow) * 32 + so] = f2fp8(v);
            }
        }
    }
}

// ---------------------------------------------------------------------------
// Last-layer GEMM (round-7 proven): relu(hb + msg @ Wt^T + bias), no h
// writes; LDS column-sum -> atomicAdd into g.
// ---------------------------------------------------------------------------
__global__ __launch_bounds__(256) void k_gemm_last(const ushort* __restrict__ A,
                                                   const ushort* __restrict__ Bt,
                                                   const float* __restrict__ bias,
                                                   const ushort* __restrict__ H,
                                                   float* __restrict__ g,
                                                   int M) {
    __shared__ ushort As[64][40];
    __shared__ ushort Bs[64][40];
    __shared__ float cols[256];
    int tid = threadIdx.x;
    int w = tid >> 6, l = tid & 63;
    int row0 = blockIdx.y * 64, col0 = blockIdx.x * 64;
    int sr = tid >> 2, sc = (tid & 3) * 8;
    int wm = (w >> 1) * 32, wn = (w & 1) * 32;
    int fr = l & 15, fk = (l >> 4) * 8;
    f32x4 acc[2][2] = {};

    for (int k0 = 0; k0 < HDIM; k0 += 32) {
        bf16x8 av = {0, 0, 0, 0, 0, 0, 0, 0};
        int gr = row0 + sr;
        if (gr < M) av = *(const bf16x8*)&A[(size_t)gr * HDIM + k0 + sc];
        *(bf16x8*)&As[sr][sc] = av;
        *(bf16x8*)&Bs[sr][sc] = *(const bf16x8*)&Bt[(size_t)(col0 + sr) * HDIM + k0 + sc];
        __syncthreads();
        bf16x8 af[2], bf[2];
#pragma unroll
        for (int mi = 0; mi < 2; mi++) af[mi] = *(const bf16x8*)&As[wm + mi * 16 + fr][fk];
#pragma unroll
        for (int ni = 0; ni < 2; ni++) bf[ni] = *(const bf16x8*)&Bs[wn + ni * 16 + fr][fk];
#pragma unroll
        for (int mi = 0; mi < 2; mi++)
#pragma unroll
            for (int ni = 0; ni < 2; ni++)
                acc[mi][ni] = __builtin_amdgcn_mfma_f32_16x16x32_bf16(af[mi], bf[ni], acc[mi][ni], 0, 0, 0);
        __syncthreads();
    }

    cols[tid] = 0.f;
    __syncthreads();
#pragma unroll
    for (int ni = 0; ni < 2; ni++) {
        int gcol = col0 + wn + ni * 16 + fr;
        float bb = bias[gcol];
        float csum = 0.f;
#pragma unroll
        for (int mi = 0; mi < 2; mi++) {
#pragma unroll
            for (int j = 0; j < 4; j++) {
                int grow = row0 + wm + mi * 16 + (l >> 4) * 4 + j;
                if (grow >= M) continue;
                size_t idx = (size_t)grow * HDIM + gcol;
                float v = acc[mi][ni][j] + bb + bf2f(H[idx]);
                csum += fmaxf(v, 0.f);
            }
        }
        atomicAdd(&cols[gcol], csum);
    }
    __syncthreads();
    if (tid < 64) atomicAdd(&g[col0 + tid], cols[col0 + tid]);
}

// ---------------------------------------------------------------------------
// Tiny MLP head (fp32)
// ---------------------------------------------------------------------------
__global__ __launch_bounds__(256) void k_mlp(const float* __restrict__ g, const float* __restrict__ w1,
                                             const float* __restrict__ b1, const float* __restrict__ w2,
                                             const float* __restrict__ b2, float* __restrict__ out, float invN) {
    __shared__ float gs[256];
    __shared__ float ts[256];
    int f = threadIdx.x;
    gs[f] = g[f] * invN;
    __syncthreads();
    float a = b1[f];
    for (int k = 0; k < 256; k++) a = fmaf(gs[k], w1[k * 256 + f], a);
    ts[f] = fmaxf(a, 0.f);
    __syncthreads();
    float o = b2[f];
    for (int k = 0; k < 256; k++) o = fmaf(ts[k], w2[k * 256 + f], o);
    out[f] = o;
}

// ---------------------------------------------------------------------------
extern "C" void kernel_launch(void* const* d_in, const int* in_sizes, int n_in,
                              void* d_out, int out_size, void* d_ws, size_t ws_size,
                              hipStream_t stream) {
    const float* x      = (const float*)d_in[0];
    const int*   src    = (const int*)d_in[1];
    const int*   dst    = (const int*)d_in[2];
    const float* w_node = (const float*)d_in[3];
    const float* b_node = (const float*)d_in[4];
    const float* w_gnn  = (const float*)d_in[5];
    const float* b_gnn  = (const float*)d_in[6];
    const float* w_p1   = (const float*)d_in[7];
    const float* b_p1   = (const float*)d_in[8];
    const float* w_p2   = (const float*)d_in[9];
    const float* b_p2   = (const float*)d_in[10];
    float* out = (float*)d_out;

    const int N = in_sizes[0] / DNODE;  // 100000
    const int E = in_sizes[1];          // 1600000

    // workspace layout (~155 MB)
    char* w = (char*)d_ws;
    ushort* hb     = (ushort*)w;            w += (size_t)N * HDIM * 2;
    ushort* msgb   = (ushort*)w;            w += (size_t)N * HDIM * 2;
    unsigned char* h8s = (unsigned char*)w; w += (size_t)NSLICE * N * 32;
    ushort* xb     = (ushort*)w;            w += (size_t)N * DNODE * 2;
    ushort* wnt    = (ushort*)w;            w += (size_t)HDIM * DNODE * 2;
    ushort* wgt    = (ushort*)w;            w += (size_t)NLAYERS * HDIM * HDIM * 2;
    int*   deg     = (int*)w;               w += (size_t)N * 4;
    int*   row_ptr = (int*)w;               w += (size_t)(N + 1) * 4;
    int*   cursor  = (int*)w;               w += (size_t)N * 4;
    int*   colx    = (int*)w;               w += (size_t)E * 4;
    float* inv_den = (float*)w;             w += (size_t)N * 4;
    float* g       = (float*)w;             w += 256 * 4;
    int*   bsum    = (int*)w;               w += 256 * 4;
    (void)ws_size; (void)n_in; (void)out_size;

    hipMemsetAsync(deg, 0, (size_t)N * 4, stream);
    hipMemsetAsync(g, 0, 256 * 4, stream);

    // deg histogram + converts (one launch)
    int degB = (E + 255) / 256;
    int n4 = N * DNODE / 4;
    int xcB = (n4 + 255) / 256;
    int wcB = DNODE / 16 + NLAYERS * (HDIM / 16);
    k_pre<<<degB + xcB + wcB, 256, 0, stream>>>(dst, deg, E, degB, x, xb, n4, xcB,
                                                w_node, wnt, w_gnn, wgt);

    // scan chain
    int nb = (N + 2047) / 2048;
    k_scan_partial<<<nb, 256, 0, stream>>>(deg, bsum, N);
    k_scan_bsum<<<1, 64, 0, stream>>>(bsum, nb);
    k_scan_final<<<nb, 256, 0, stream>>>(deg, bsum, row_ptr, cursor, inv_den, N, E);

    // CSR fill — XCD-partitioned for colx L2 residency
    int npp = (N + NPART - 1) / NPART;
    int nslices = 256;
    k_fill_part<<<NPART * nslices, 256, 0, stream>>>(src, dst, cursor, colx, E, npp, nslices);

    // node projection -> hb + h8s
    dim3 gg(HDIM / 64, (N + 63) / 64);
    k_gemm_mfma<false, false, true><<<gg, 256, 0, stream>>>(xb, wnt, b_node, hb, h8s, N, DNODE);

    // GNN layers
    int nagg = NSLICE * ((N + 63) / 64);
    for (int l = 0; l < NLAYERS; l++) {
        k_agg_slice<<<nagg, 256, 0, stream>>>(h8s, row_ptr, colx, inv_den, msgb, N);
        const ushort* Bt = wgt + (size_t)l * HDIM * HDIM;
        const float* bg = b_gnn + (size_t)l * HDIM;
        if (l < NLAYERS - 1)
            k_gemm_mfma<true, true, true><<<gg, 256, 0, stream>>>(msgb, Bt, bg, hb, h8s, N, HDIM);
        else
            k_gemm_last<<<gg, 256, 0, stream>>>(msgb, Bt, bg, hb, g, N);
    }

    k_mlp<<<1, 256, 0, stream>>>(g, w_p1, b_p1, w_p2, b_p2, out, 1.0f / (float)N);
}

// Round 10
// 607.950 us; speedup vs baseline: 1.4907x; 1.1724x over previous
//
#include <hip/hip_runtime.h>
#include <hip/hip_bf16.h>
#include <cstdint>
#include <cstddef>

#define DNODE 64
#define HDIM 256
#define NLAYERS 3
#define NPART 8

typedef __attribute__((ext_vector_type(8))) short bf16x8;
typedef __attribute__((ext_vector_type(4))) float f32x4;

__device__ __forceinline__ ushort f2bf(float f) {
    __hip_bfloat16 b = __float2bfloat16(f);
    return *(ushort*)&b;
}
__device__ __forceinline__ float bf2f(ushort u) {
    return __uint_as_float((uint32_t)u << 16);
}
__device__ __forceinline__ unsigned char f2fp8(float f) {
    int p = __builtin_amdgcn_cvt_pk_fp8_f32(f, f, 0, false);
    return (unsigned char)(p & 0xFF);
}

// ---------------------------------------------------------------------------
// k_pre: deg histogram + x->bf16 convert + weight transposes, one launch
// ---------------------------------------------------------------------------
__global__ __launch_bounds__(256) void k_pre(const int* __restrict__ edst, int* __restrict__ deg, int E, int degB,
                                             const float* __restrict__ x, ushort* __restrict__ xb, int n4, int xcB,
                                             const float* __restrict__ w_node, ushort* __restrict__ wnt,
                                             const float* __restrict__ w_gnn, ushort* __restrict__ wgt) {
    int b = blockIdx.x, tid = threadIdx.x;
    if (b < degB) {
        int e = b * 256 + tid;
        if (e < E) atomicAdd(&deg[edst[e]], 1);
    } else if (b < degB + xcB) {
        int i = (b - degB) * 256 + tid;
        if (i < n4) {
            float4 v = *(const float4*)&x[(size_t)i * 4];
            ushort4 o;
            o.x = f2bf(v.x); o.y = f2bf(v.y); o.z = f2bf(v.z); o.w = f2bf(v.w);
            *(ushort4*)&xb[(size_t)i * 4] = o;
        }
    } else {
        int wb = b - degB - xcB;
        int n = tid;
        if (wb < DNODE / 16) {
            int k0 = wb * 16;
#pragma unroll
            for (int i = 0; i < 16; i++)
                wnt[(size_t)n * DNODE + k0 + i] = f2bf(w_node[(size_t)(k0 + i) * HDIM + n]);
        } else {
            wb -= DNODE / 16;
            int l = wb >> 4, k0 = (wb & 15) * 16;
            const float* s = w_gnn + (size_t)l * HDIM * HDIM;
            ushort* d = wgt + (size_t)l * HDIM * HDIM;
#pragma unroll
            for (int i = 0; i < 16; i++)
                d[(size_t)n * HDIM + k0 + i] = f2bf(s[(size_t)(k0 + i) * HDIM + n]);
        }
    }
}

// ---------------------------------------------------------------------------
// k_wc: Wc = Wn @ W0 (combined x->hw0 weight) and bc = bn @ W0.
// wct stored transposed bf16 [256][64] for MFMA B-operand.
// ---------------------------------------------------------------------------
__global__ __launch_bounds__(256) void k_wc(const float* __restrict__ wn, const float* __restrict__ w0,
                                            const float* __restrict__ bn,
                                            ushort* __restrict__ wct, float* __restrict__ bc) {
    int n = threadIdx.x;
    int k = blockIdx.x;
    if (k < DNODE) {
        float s = 0.f;
        for (int j = 0; j < HDIM; j++) s = fmaf(wn[(size_t)k * HDIM + j], w0[(size_t)j * HDIM + n], s);
        wct[(size_t)n * DNODE + k] = f2bf(s);
    } else {
        float s = 0.f;
        for (int j = 0; j < HDIM; j++) s = fmaf(bn[j], w0[(size_t)j * HDIM + n], s);
        bc[n] = s;
    }
}

// ---------------------------------------------------------------------------
// Scan chain (unchanged, proven)
// ---------------------------------------------------------------------------
__global__ __launch_bounds__(256) void k_scan_partial(const int* __restrict__ deg, int* __restrict__ bsum, int n) {
    __shared__ int sd[256];
    int tid = threadIdx.x;
    int base = blockIdx.x * 2048 + tid * 8;
    int s = 0;
#pragma unroll
    for (int j = 0; j < 8; j++) {
        int idx = base + j;
        if (idx < n) s += deg[idx];
    }
    sd[tid] = s;
    __syncthreads();
    for (int off = 128; off > 0; off >>= 1) {
        if (tid < off) sd[tid] += sd[tid + off];
        __syncthreads();
    }
    if (tid == 0) bsum[blockIdx.x] = sd[0];
}

__global__ void k_scan_bsum(int* bsum, int nb) {
    if (threadIdx.x == 0 && blockIdx.x == 0) {
        int run = 0;
        for (int i = 0; i < nb; i++) { int v = bsum[i]; bsum[i] = run; run += v; }
    }
}

__global__ __launch_bounds__(256) void k_scan_final(const int* __restrict__ deg, const int* __restrict__ bsum,
                                                    int* __restrict__ row_ptr, int* __restrict__ cursor,
                                                    float* __restrict__ inv_den, int n, int Etot) {
    __shared__ int tsum[256];
    int tid = threadIdx.x;
    int base = blockIdx.x * 2048 + tid * 8;
    int loc[8], dv[8];
    int s = 0;
#pragma unroll
    for (int j = 0; j < 8; j++) {
        int idx = base + j;
        int v = (idx < n) ? deg[idx] : 0;
        dv[j] = v;
        loc[j] = s;
        s += v;
    }
    tsum[tid] = s;
    __syncthreads();
    for (int off = 1; off < 256; off <<= 1) {
        int t = (tid >= off) ? tsum[tid - off] : 0;
        __syncthreads();
        tsum[tid] += t;
        __syncthreads();
    }
    int off0 = bsum[blockIdx.x] + (tid ? tsum[tid - 1] : 0);
#pragma unroll
    for (int j = 0; j < 8; j++) {
        int idx = base + j;
        if (idx < n) {
            int rp = off0 + loc[j];
            row_ptr[idx] = rp;
            cursor[idx] = rp;
            int d = dv[j];
            inv_den[idx] = 1.0f / (float)(d > 0 ? d : 1);
        }
    }
    if (blockIdx.x == 0 && tid == 0) row_ptr[n] = Etot;
}

// ---------------------------------------------------------------------------
// k_fill_part: XCD-partitioned CSR fill (round-7 proven)
// ---------------------------------------------------------------------------
__global__ __launch_bounds__(256) void k_fill_part(const int* __restrict__ esrc, const int* __restrict__ edst,
                                                   int* __restrict__ cursor, int* __restrict__ colx,
                                                   int E, int npp, int nslices) {
    int part = blockIdx.x & (NPART - 1);
    int slice = blockIdx.x / NPART;
    int lo = part * npp;
    int hi = lo + npp;
    int stride = nslices * 256;
    for (int e = slice * 256 + (int)threadIdx.x; e < E; e += stride) {
        int d = edst[e];
        if (d >= lo && d < hi) {
            int p = atomicAdd(&cursor[d], 1);
            colx[p] = esrc[e];
        }
    }
}

// ---------------------------------------------------------------------------
// k_proj: fused node projection. h = x@Wn + bn (bf16) AND hw0 = x@Wc + bc
// (fp8). Shared A-tile (x), two B operands, K=64. Proven staging/fragments.
// ---------------------------------------------------------------------------
__global__ __launch_bounds__(256) void k_proj(const ushort* __restrict__ xb,
                                              const ushort* __restrict__ wnt,
                                              const ushort* __restrict__ wct,
                                              const float* __restrict__ bn,
                                              const float* __restrict__ bc,
                                              ushort* __restrict__ hb,
                                              unsigned char* __restrict__ hw8,
                                              int M) {
    __shared__ ushort As[64][40];
    __shared__ ushort Bs[64][40];
    __shared__ ushort Cs[64][40];
    int tid = threadIdx.x;
    int w = tid >> 6, l = tid & 63;
    int row0 = blockIdx.y * 64, col0 = blockIdx.x * 64;
    int sr = tid >> 2, sc = (tid & 3) * 8;
    int wm = (w >> 1) * 32, wn_ = (w & 1) * 32;
    int fr = l & 15, fk = (l >> 4) * 8;
    f32x4 acch[2][2] = {};
    f32x4 accw[2][2] = {};

    for (int k0 = 0; k0 < DNODE; k0 += 32) {
        bf16x8 av = {0, 0, 0, 0, 0, 0, 0, 0};
        int gr = row0 + sr;
        if (gr < M) av = *(const bf16x8*)&xb[(size_t)gr * DNODE + k0 + sc];
        *(bf16x8*)&As[sr][sc] = av;
        *(bf16x8*)&Bs[sr][sc] = *(const bf16x8*)&wnt[(size_t)(col0 + sr) * DNODE + k0 + sc];
        *(bf16x8*)&Cs[sr][sc] = *(const bf16x8*)&wct[(size_t)(col0 + sr) * DNODE + k0 + sc];
        __syncthreads();
        bf16x8 af[2], bff[2], cf[2];
#pragma unroll
        for (int mi = 0; mi < 2; mi++) af[mi] = *(const bf16x8*)&As[wm + mi * 16 + fr][fk];
#pragma unroll
        for (int ni = 0; ni < 2; ni++) {
            bff[ni] = *(const bf16x8*)&Bs[wn_ + ni * 16 + fr][fk];
            cf[ni] = *(const bf16x8*)&Cs[wn_ + ni * 16 + fr][fk];
        }
#pragma unroll
        for (int mi = 0; mi < 2; mi++)
#pragma unroll
            for (int ni = 0; ni < 2; ni++) {
                acch[mi][ni] = __builtin_amdgcn_mfma_f32_16x16x32_bf16(af[mi], bff[ni], acch[mi][ni], 0, 0, 0);
                accw[mi][ni] = __builtin_amdgcn_mfma_f32_16x16x32_bf16(af[mi], cf[ni], accw[mi][ni], 0, 0, 0);
            }
        __syncthreads();
    }

#pragma unroll
    for (int ni = 0; ni < 2; ni++) {
        int gcol = col0 + wn_ + ni * 16 + fr;
        float bbh = bn[gcol];
        float bbw = bc[gcol];
#pragma unroll
        for (int mi = 0; mi < 2; mi++) {
#pragma unroll
            for (int j = 0; j < 4; j++) {
                int grow = row0 + wm + mi * 16 + (l >> 4) * 4 + j;
                if (grow >= M) continue;
                size_t idx = (size_t)grow * HDIM + gcol;
                hb[idx] = f2bf(acch[mi][ni][j] + bbh);
                hw8[idx] = f2fp8(accw[mi][ni][j] + bbw);
            }
        }
    }
}

// ---------------------------------------------------------------------------
// k_gemm_hw: hw8 = fp8(hb @ Wt^T). Proven 64x64-tile MFMA body; epilogue
// writes fp8 only (no bias, no residual, no in-place hazard).
// ---------------------------------------------------------------------------
__global__ __launch_bounds__(256) void k_gemm_hw(const ushort* __restrict__ A,
                                                 const ushort* __restrict__ Bt,
                                                 unsigned char* __restrict__ hw8,
                                                 int M) {
    __shared__ ushort As[64][40];
    __shared__ ushort Bs[64][40];
    int tid = threadIdx.x;
    int w = tid >> 6, l = tid & 63;
    int row0 = blockIdx.y * 64, col0 = blockIdx.x * 64;
    int sr = tid >> 2, sc = (tid & 3) * 8;
    int wm = (w >> 1) * 32, wn = (w & 1) * 32;
    int fr = l & 15, fk = (l >> 4) * 8;
    f32x4 acc[2][2] = {};

    for (int k0 = 0; k0 < HDIM; k0 += 32) {
        bf16x8 av = {0, 0, 0, 0, 0, 0, 0, 0};
        int gr = row0 + sr;
        if (gr < M) av = *(const bf16x8*)&A[(size_t)gr * HDIM + k0 + sc];
        *(bf16x8*)&As[sr][sc] = av;
        *(bf16x8*)&Bs[sr][sc] = *(const bf16x8*)&Bt[(size_t)(col0 + sr) * HDIM + k0 + sc];
        __syncthreads();
        bf16x8 af[2], bf[2];
#pragma unroll
        for (int mi = 0; mi < 2; mi++) af[mi] = *(const bf16x8*)&As[wm + mi * 16 + fr][fk];
#pragma unroll
        for (int ni = 0; ni < 2; ni++) bf[ni] = *(const bf16x8*)&Bs[wn + ni * 16 + fr][fk];
#pragma unroll
        for (int mi = 0; mi < 2; mi++)
#pragma unroll
            for (int ni = 0; ni < 2; ni++)
                acc[mi][ni] = __builtin_amdgcn_mfma_f32_16x16x32_bf16(af[mi], bf[ni], acc[mi][ni], 0, 0, 0);
        __syncthreads();
    }

#pragma unroll
    for (int ni = 0; ni < 2; ni++) {
        int gcol = col0 + wn + ni * 16 + fr;
#pragma unroll
        for (int mi = 0; mi < 2; mi++) {
#pragma unroll
            for (int j = 0; j < 4; j++) {
                int grow = row0 + wm + mi * 16 + (l >> 4) * 4 + j;
                if (grow >= M) continue;
                hw8[(size_t)grow * HDIM + gcol] = f2fp8(acc[mi][ni][j]);
            }
        }
    }
}

// ---------------------------------------------------------------------------
// k_agg: gather-mean of hw8 (proven round-5 loop) fused with the full layer
// epilogue: h = relu(h + mean + bias). LAST: LDS column-sum -> g instead of
// writing h (grid-stride tiles, one flush per block).
// ---------------------------------------------------------------------------
__device__ __forceinline__ void acc_fp8x16(uint4 v, float* acc) {
    uint32_t d[4] = {v.x, v.y, v.z, v.w};
#pragma unroll
    for (int i = 0; i < 4; i++) {
        auto lo = __builtin_amdgcn_cvt_pk_f32_fp8(d[i], false);
        auto hi = __builtin_amdgcn_cvt_pk_f32_fp8(d[i], true);
        acc[i * 4 + 0] += lo[0];
        acc[i * 4 + 1] += lo[1];
        acc[i * 4 + 2] += hi[0];
        acc[i * 4 + 3] += hi[1];
    }
}

template <bool LAST>
__global__ __launch_bounds__(256) void k_agg(const unsigned char* __restrict__ hw8,
                                             const int* __restrict__ row_ptr,
                                             const int* __restrict__ colx,
                                             const float* __restrict__ inv_den,
                                             ushort* __restrict__ hb,
                                             const float* __restrict__ bias,
                                             float* __restrict__ g,
                                             int N, int ntiles) {
    __shared__ float cols[256];
    int tid = threadIdx.x;
    if (LAST) {
        cols[tid] = 0.f;
        __syncthreads();
    }
    int f = tid & 15;
    int gbase = tid & 48;
    const unsigned char* hp = hw8 + (size_t)f * 16;

    float bar[16];
#pragma unroll
    for (int k = 0; k < 16; k++) bar[k] = bias[f * 16 + k];

    for (int tile = blockIdx.x; tile < ntiles; tile += gridDim.x) {
        int node = tile * 16 + (tid >> 4);
        if (node < N) {
            int s = row_ptr[node], e = row_ptr[node + 1];
            float acc[16] = {};
            for (int base = s; base < e; base += 16) {
                int rem = e - base;
                int cnt = rem > 16 ? 16 : rem;
                int cv = (f < cnt) ? colx[base + f] : 0;
                int t = 0;
                for (; t + 3 < cnt; t += 4) {
                    int c0 = __shfl(cv, gbase + t);
                    int c1 = __shfl(cv, gbase + t + 1);
                    int c2 = __shfl(cv, gbase + t + 2);
                    int c3 = __shfl(cv, gbase + t + 3);
                    uint4 v0 = *(const uint4*)&hp[(size_t)c0 * HDIM];
                    uint4 v1 = *(const uint4*)&hp[(size_t)c1 * HDIM];
                    uint4 v2 = *(const uint4*)&hp[(size_t)c2 * HDIM];
                    uint4 v3 = *(const uint4*)&hp[(size_t)c3 * HDIM];
                    acc_fp8x16(v0, acc);
                    acc_fp8x16(v1, acc);
                    acc_fp8x16(v2, acc);
                    acc_fp8x16(v3, acc);
                }
                for (; t < cnt; t++) {
                    int c0 = __shfl(cv, gbase + t);
                    uint4 v0 = *(const uint4*)&hp[(size_t)c0 * HDIM];
                    acc_fp8x16(v0, acc);
                }
            }

            float inv = inv_den[node];
            ushort* hrow = &hb[(size_t)node * HDIM + f * 16];
            bf16x8 h0 = *(const bf16x8*)&hrow[0];
            bf16x8 h1 = *(const bf16x8*)&hrow[8];
            float v[16];
#pragma unroll
            for (int k = 0; k < 8; k++) {
                v[k] = fmaxf(acc[k] * inv + bf2f((ushort)h0[k]) + bar[k], 0.f);
                v[k + 8] = fmaxf(acc[k + 8] * inv + bf2f((ushort)h1[k]) + bar[k + 8], 0.f);
            }
            if (LAST) {
#pragma unroll
                for (int k = 0; k < 16; k++) atomicAdd(&cols[f * 16 + k], v[k]);
            } else {
                ushort o[16];
#pragma unroll
                for (int k = 0; k < 16; k++) o[k] = f2bf(v[k]);
                *(uint4*)&hrow[0] = *(uint4*)&o[0];
                *(uint4*)&hrow[8] = *(uint4*)&o[8];
            }
        }
    }
    if (LAST) {
        __syncthreads();
        atomicAdd(&g[tid], cols[tid]);
    }
}

// ---------------------------------------------------------------------------
// Tiny MLP head (fp32)
// ---------------------------------------------------------------------------
__global__ __launch_bounds__(256) void k_mlp(const float* __restrict__ g, const float* __restrict__ w1,
                                             const float* __restrict__ b1, const float* __restrict__ w2,
                                             const float* __restrict__ b2, float* __restrict__ out, float invN) {
    __shared__ float gs[256];
    __shared__ float ts[256];
    int f = threadIdx.x;
    gs[f] = g[f] * invN;
    __syncthreads();
    float a = b1[f];
    for (int k = 0; k < 256; k++) a = fmaf(gs[k], w1[k * 256 + f], a);
    ts[f] = fmaxf(a, 0.f);
    __syncthreads();
    float o = b2[f];
    for (int k = 0; k < 256; k++) o = fmaf(ts[k], w2[k * 256 + f], o);
    out[f] = o;
}

// ---------------------------------------------------------------------------
extern "C" void kernel_launch(void* const* d_in, const int* in_sizes, int n_in,
                              void* d_out, int out_size, void* d_ws, size_t ws_size,
                              hipStream_t stream) {
    const float* x      = (const float*)d_in[0];
    const int*   src    = (const int*)d_in[1];
    const int*   dst    = (const int*)d_in[2];
    const float* w_node = (const float*)d_in[3];
    const float* b_node = (const float*)d_in[4];
    const float* w_gnn  = (const float*)d_in[5];
    const float* b_gnn  = (const float*)d_in[6];
    const float* w_p1   = (const float*)d_in[7];
    const float* b_p1   = (const float*)d_in[8];
    const float* w_p2   = (const float*)d_in[9];
    const float* b_p2   = (const float*)d_in[10];
    float* out = (float*)d_out;

    const int N = in_sizes[0] / DNODE;  // 100000
    const int E = in_sizes[1];          // 1600000

    // workspace layout (~98 MB)
    char* w = (char*)d_ws;
    ushort* hb     = (ushort*)w;            w += (size_t)N * HDIM * 2;
    unsigned char* hw8 = (unsigned char*)w; w += (size_t)N * HDIM;
    ushort* xb     = (ushort*)w;            w += (size_t)N * DNODE * 2;
    ushort* wnt    = (ushort*)w;            w += (size_t)HDIM * DNODE * 2;
    ushort* wct    = (ushort*)w;            w += (size_t)HDIM * DNODE * 2;
    ushort* wgt    = (ushort*)w;            w += (size_t)NLAYERS * HDIM * HDIM * 2;
    float* bc      = (float*)w;             w += 256 * 4;
    int*   deg     = (int*)w;               w += (size_t)N * 4;
    int*   row_ptr = (int*)w;               w += (size_t)(N + 1) * 4;
    int*   cursor  = (int*)w;               w += (size_t)N * 4;
    int*   colx    = (int*)w;               w += (size_t)E * 4;
    float* inv_den = (float*)w;             w += (size_t)N * 4;
    float* g       = (float*)w;             w += 256 * 4;
    int*   bsum    = (int*)w;               w += 256 * 4;
    (void)ws_size; (void)n_in; (void)out_size;

    hipMemsetAsync(deg, 0, (size_t)N * 4, stream);
    hipMemsetAsync(g, 0, 256 * 4, stream);

    // deg histogram + converts (one launch)
    int degB = (E + 255) / 256;
    int n4 = N * DNODE / 4;
    int xcB = (n4 + 255) / 256;
    int wcB = DNODE / 16 + NLAYERS * (HDIM / 16);
    k_pre<<<degB + xcB + wcB, 256, 0, stream>>>(dst, deg, E, degB, x, xb, n4, xcB,
                                                w_node, wnt, w_gnn, wgt);

    // combined weight Wc = Wn @ W0, bc = bn @ W0
    k_wc<<<DNODE + 1, 256, 0, stream>>>(w_node, w_gnn, b_node, wct, bc);

    // scan chain
    int nb = (N + 2047) / 2048;
    k_scan_partial<<<nb, 256, 0, stream>>>(deg, bsum, N);
    k_scan_bsum<<<1, 64, 0, stream>>>(bsum, nb);
    k_scan_final<<<nb, 256, 0, stream>>>(deg, bsum, row_ptr, cursor, inv_den, N, E);

    // CSR fill — XCD-partitioned for colx L2 residency
    int npp = (N + NPART - 1) / NPART;
    int nslices = 256;
    k_fill_part<<<NPART * nslices, 256, 0, stream>>>(src, dst, cursor, colx, E, npp, nslices);

    // fused node projection: hb = x@Wn + bn ; hw8 = fp8(x@Wc + bc)
    dim3 gg(HDIM / 64, (N + 63) / 64);
    k_proj<<<gg, 256, 0, stream>>>(xb, wnt, wct, b_node, bc, hb, hw8, N);

    // GNN layers: agg(hw8) fused with residual+bias+relu; gemm produces next hw8
    int ntiles = (N + 15) / 16;
    for (int l = 0; l < NLAYERS; l++) {
        const float* bg = b_gnn + (size_t)l * HDIM;
        if (l < NLAYERS - 1) {
            k_agg<false><<<ntiles, 256, 0, stream>>>(hw8, row_ptr, colx, inv_den, hb, bg, nullptr, N, ntiles);
            k_gemm_hw<<<gg, 256, 0, stream>>>(hb, wgt + (size_t)(l + 1) * HDIM * HDIM, hw8, N);
        } else {
            k_agg<true><<<2048, 256, 0, stream>>>(hw8, row_ptr, colx, inv_den, hb, bg, g, N, ntiles);
        }
    }

    k_mlp<<<1, 256, 0, stream>>>(g, w_p1, b_p1, w_p2, b_p2, out, 1.0f / (float)N);
}

// Round 11
// 589.634 us; speedup vs baseline: 1.5370x; 1.0311x over previous
//
#include <hip/hip_runtime.h>
#include <hip/hip_bf16.h>
#include <cstdint>
#include <cstddef>

#define DNODE 64
#define HDIM 256
#define NLAYERS 3
#define NPART 8

typedef __attribute__((ext_vector_type(8))) short bf16x8;
typedef __attribute__((ext_vector_type(4))) float f32x4;

__device__ __forceinline__ ushort f2bf(float f) {
    __hip_bfloat16 b = __float2bfloat16(f);
    return *(ushort*)&b;
}
__device__ __forceinline__ float bf2f(ushort u) {
    return __uint_as_float((uint32_t)u << 16);
}
__device__ __forceinline__ unsigned char f2fp8(float f) {
    int p = __builtin_amdgcn_cvt_pk_fp8_f32(f, f, 0, false);
    return (unsigned char)(p & 0xFF);
}

// ---------------------------------------------------------------------------
// k_pre: deg histogram + x->bf16 + weight transposes + Wc=Wn@W0 / bc=bn@W0
// ---------------------------------------------------------------------------
__global__ __launch_bounds__(256) void k_pre(const int* __restrict__ edst, int* __restrict__ deg, int E, int degB,
                                             const float* __restrict__ x, ushort* __restrict__ xb, int n4, int xcB,
                                             const float* __restrict__ w_node, ushort* __restrict__ wnt,
                                             const float* __restrict__ w_gnn, ushort* __restrict__ wgt, int wcB,
                                             ushort* __restrict__ wct, float* __restrict__ bc,
                                             const float* __restrict__ b_node) {
    int b = blockIdx.x, tid = threadIdx.x;
    if (b < degB) {
        int e = b * 256 + tid;
        if (e < E) atomicAdd(&deg[edst[e]], 1);
    } else if (b < degB + xcB) {
        int i = (b - degB) * 256 + tid;
        if (i < n4) {
            float4 v = *(const float4*)&x[(size_t)i * 4];
            ushort4 o;
            o.x = f2bf(v.x); o.y = f2bf(v.y); o.z = f2bf(v.z); o.w = f2bf(v.w);
            *(ushort4*)&xb[(size_t)i * 4] = o;
        }
    } else if (b < degB + xcB + wcB) {
        int wb = b - degB - xcB;
        int n = tid;
        if (wb < DNODE / 16) {
            int k0 = wb * 16;
#pragma unroll
            for (int i = 0; i < 16; i++)
                wnt[(size_t)n * DNODE + k0 + i] = f2bf(w_node[(size_t)(k0 + i) * HDIM + n]);
        } else {
            wb -= DNODE / 16;
            int l = wb >> 4, k0 = (wb & 15) * 16;
            const float* s = w_gnn + (size_t)l * HDIM * HDIM;
            ushort* d = wgt + (size_t)l * HDIM * HDIM;
#pragma unroll
            for (int i = 0; i < 16; i++)
                d[(size_t)n * HDIM + k0 + i] = f2bf(s[(size_t)(k0 + i) * HDIM + n]);
        }
    } else {
        // combined weight: wct[n][k] = sum_j Wn[k][j]*W0[j][n]; bc = bn@W0
        int k = b - degB - xcB - wcB;   // 0..DNODE
        int n = tid;
        if (k < DNODE) {
            float s = 0.f;
            for (int j = 0; j < HDIM; j++) s = fmaf(w_node[(size_t)k * HDIM + j], w_gnn[(size_t)j * HDIM + n], s);
            wct[(size_t)n * DNODE + k] = f2bf(s);
        } else {
            float s = 0.f;
            for (int j = 0; j < HDIM; j++) s = fmaf(b_node[j], w_gnn[(size_t)j * HDIM + n], s);
            bc[n] = s;
        }
    }
}

// ---------------------------------------------------------------------------
// Scan chain (unchanged, proven)
// ---------------------------------------------------------------------------
__global__ __launch_bounds__(256) void k_scan_partial(const int* __restrict__ deg, int* __restrict__ bsum, int n) {
    __shared__ int sd[256];
    int tid = threadIdx.x;
    int base = blockIdx.x * 2048 + tid * 8;
    int s = 0;
#pragma unroll
    for (int j = 0; j < 8; j++) {
        int idx = base + j;
        if (idx < n) s += deg[idx];
    }
    sd[tid] = s;
    __syncthreads();
    for (int off = 128; off > 0; off >>= 1) {
        if (tid < off) sd[tid] += sd[tid + off];
        __syncthreads();
    }
    if (tid == 0) bsum[blockIdx.x] = sd[0];
}

__global__ void k_scan_bsum(int* bsum, int nb) {
    if (threadIdx.x == 0 && blockIdx.x == 0) {
        int run = 0;
        for (int i = 0; i < nb; i++) { int v = bsum[i]; bsum[i] = run; run += v; }
    }
}

__global__ __launch_bounds__(256) void k_scan_final(const int* __restrict__ deg, const int* __restrict__ bsum,
                                                    int* __restrict__ row_ptr, int* __restrict__ cursor,
                                                    float* __restrict__ inv_den, int n, int Etot) {
    __shared__ int tsum[256];
    int tid = threadIdx.x;
    int base = blockIdx.x * 2048 + tid * 8;
    int loc[8], dv[8];
    int s = 0;
#pragma unroll
    for (int j = 0; j < 8; j++) {
        int idx = base + j;
        int v = (idx < n) ? deg[idx] : 0;
        dv[j] = v;
        loc[j] = s;
        s += v;
    }
    tsum[tid] = s;
    __syncthreads();
    for (int off = 1; off < 256; off <<= 1) {
        int t = (tid >= off) ? tsum[tid - off] : 0;
        __syncthreads();
        tsum[tid] += t;
        __syncthreads();
    }
    int off0 = bsum[blockIdx.x] + (tid ? tsum[tid - 1] : 0);
#pragma unroll
    for (int j = 0; j < 8; j++) {
        int idx = base + j;
        if (idx < n) {
            int rp = off0 + loc[j];
            row_ptr[idx] = rp;
            cursor[idx] = rp;
            int d = dv[j];
            inv_den[idx] = 1.0f / (float)(d > 0 ? d : 1);
        }
    }
    if (blockIdx.x == 0 && tid == 0) row_ptr[n] = Etot;
}

// ---------------------------------------------------------------------------
// k_fill_part: XCD-partitioned CSR fill (round-7 proven)
// ---------------------------------------------------------------------------
__global__ __launch_bounds__(256) void k_fill_part(const int* __restrict__ esrc, const int* __restrict__ edst,
                                                   int* __restrict__ cursor, int* __restrict__ colx,
                                                   int E, int npp, int nslices) {
    int part = blockIdx.x & (NPART - 1);
    int slice = blockIdx.x / NPART;
    int lo = part * npp;
    int hi = lo + npp;
    int stride = nslices * 256;
    for (int e = slice * 256 + (int)threadIdx.x; e < E; e += stride) {
        int d = edst[e];
        if (d >= lo && d < hi) {
            int p = atomicAdd(&cursor[d], 1);
            colx[p] = esrc[e];
        }
    }
}

// ---------------------------------------------------------------------------
// k_proj: fused node projection. h = x@Wn + bn (bf16) AND hw0 = x@Wc + bc
// (fp8). Shared A-tile (x), two B operands, K=64. (round-10 proven)
// ---------------------------------------------------------------------------
__global__ __launch_bounds__(256) void k_proj(const ushort* __restrict__ xb,
                                              const ushort* __restrict__ wnt,
                                              const ushort* __restrict__ wct,
                                              const float* __restrict__ bn,
                                              const float* __restrict__ bc,
                                              ushort* __restrict__ hb,
                                              unsigned char* __restrict__ hw8,
                                              int M) {
    __shared__ ushort As[64][40];
    __shared__ ushort Bs[64][40];
    __shared__ ushort Cs[64][40];
    int tid = threadIdx.x;
    int w = tid >> 6, l = tid & 63;
    int row0 = blockIdx.y * 64, col0 = blockIdx.x * 64;
    int sr = tid >> 2, sc = (tid & 3) * 8;
    int wm = (w >> 1) * 32, wn_ = (w & 1) * 32;
    int fr = l & 15, fk = (l >> 4) * 8;
    f32x4 acch[2][2] = {};
    f32x4 accw[2][2] = {};

    for (int k0 = 0; k0 < DNODE; k0 += 32) {
        bf16x8 av = {0, 0, 0, 0, 0, 0, 0, 0};
        int gr = row0 + sr;
        if (gr < M) av = *(const bf16x8*)&xb[(size_t)gr * DNODE + k0 + sc];
        *(bf16x8*)&As[sr][sc] = av;
        *(bf16x8*)&Bs[sr][sc] = *(const bf16x8*)&wnt[(size_t)(col0 + sr) * DNODE + k0 + sc];
        *(bf16x8*)&Cs[sr][sc] = *(const bf16x8*)&wct[(size_t)(col0 + sr) * DNODE + k0 + sc];
        __syncthreads();
        bf16x8 af[2], bff[2], cf[2];
#pragma unroll
        for (int mi = 0; mi < 2; mi++) af[mi] = *(const bf16x8*)&As[wm + mi * 16 + fr][fk];
#pragma unroll
        for (int ni = 0; ni < 2; ni++) {
            bff[ni] = *(const bf16x8*)&Bs[wn_ + ni * 16 + fr][fk];
            cf[ni] = *(const bf16x8*)&Cs[wn_ + ni * 16 + fr][fk];
        }
#pragma unroll
        for (int mi = 0; mi < 2; mi++)
#pragma unroll
            for (int ni = 0; ni < 2; ni++) {
                acch[mi][ni] = __builtin_amdgcn_mfma_f32_16x16x32_bf16(af[mi], bff[ni], acch[mi][ni], 0, 0, 0);
                accw[mi][ni] = __builtin_amdgcn_mfma_f32_16x16x32_bf16(af[mi], cf[ni], accw[mi][ni], 0, 0, 0);
            }
        __syncthreads();
    }

#pragma unroll
    for (int ni = 0; ni < 2; ni++) {
        int gcol = col0 + wn_ + ni * 16 + fr;
        float bbh = bn[gcol];
        float bbw = bc[gcol];
#pragma unroll
        for (int mi = 0; mi < 2; mi++) {
#pragma unroll
            for (int j = 0; j < 4; j++) {
                int grow = row0 + wm + mi * 16 + (l >> 4) * 4 + j;
                if (grow >= M) continue;
                size_t idx = (size_t)grow * HDIM + gcol;
                hb[idx] = f2bf(acch[mi][ni][j] + bbh);
                hw8[idx] = f2fp8(accw[mi][ni][j] + bbw);
            }
        }
    }
}

// ---------------------------------------------------------------------------
// k_gemm_hw: hw8 = fp8(hb @ Wt^T). (round-10 proven)
// ---------------------------------------------------------------------------
__global__ __launch_bounds__(256) void k_gemm_hw(const ushort* __restrict__ A,
                                                 const ushort* __restrict__ Bt,
                                                 unsigned char* __restrict__ hw8,
                                                 int M) {
    __shared__ ushort As[64][40];
    __shared__ ushort Bs[64][40];
    int tid = threadIdx.x;
    int w = tid >> 6, l = tid & 63;
    int row0 = blockIdx.y * 64, col0 = blockIdx.x * 64;
    int sr = tid >> 2, sc = (tid & 3) * 8;
    int wm = (w >> 1) * 32, wn = (w & 1) * 32;
    int fr = l & 15, fk = (l >> 4) * 8;
    f32x4 acc[2][2] = {};

    for (int k0 = 0; k0 < HDIM; k0 += 32) {
        bf16x8 av = {0, 0, 0, 0, 0, 0, 0, 0};
        int gr = row0 + sr;
        if (gr < M) av = *(const bf16x8*)&A[(size_t)gr * HDIM + k0 + sc];
        *(bf16x8*)&As[sr][sc] = av;
        *(bf16x8*)&Bs[sr][sc] = *(const bf16x8*)&Bt[(size_t)(col0 + sr) * HDIM + k0 + sc];
        __syncthreads();
        bf16x8 af[2], bf[2];
#pragma unroll
        for (int mi = 0; mi < 2; mi++) af[mi] = *(const bf16x8*)&As[wm + mi * 16 + fr][fk];
#pragma unroll
        for (int ni = 0; ni < 2; ni++) bf[ni] = *(const bf16x8*)&Bs[wn + ni * 16 + fr][fk];
#pragma unroll
        for (int mi = 0; mi < 2; mi++)
#pragma unroll
            for (int ni = 0; ni < 2; ni++)
                acc[mi][ni] = __builtin_amdgcn_mfma_f32_16x16x32_bf16(af[mi], bf[ni], acc[mi][ni], 0, 0, 0);
        __syncthreads();
    }

#pragma unroll
    for (int ni = 0; ni < 2; ni++) {
        int gcol = col0 + wn + ni * 16 + fr;
#pragma unroll
        for (int mi = 0; mi < 2; mi++) {
#pragma unroll
            for (int j = 0; j < 4; j++) {
                int grow = row0 + wm + mi * 16 + (l >> 4) * 4 + j;
                if (grow >= M) continue;
                hw8[(size_t)grow * HDIM + gcol] = f2fp8(acc[mi][ni][j]);
            }
        }
    }
}

// ---------------------------------------------------------------------------
// k_agg: gather-mean of hw8 fused with h = relu(h + mean + bias).
// LAST: per-thread register csum across tiles, ONE LDS-reduce + global
// atomic flush per block (no per-node atomics). Bias loaded in epilogue
// (not held across gather loop) to keep VGPR low for latency hiding.
// ---------------------------------------------------------------------------
__device__ __forceinline__ void acc_fp8x16(uint4 v, float* acc) {
    uint32_t d[4] = {v.x, v.y, v.z, v.w};
#pragma unroll
    for (int i = 0; i < 4; i++) {
        auto lo = __builtin_amdgcn_cvt_pk_f32_fp8(d[i], false);
        auto hi = __builtin_amdgcn_cvt_pk_f32_fp8(d[i], true);
        acc[i * 4 + 0] += lo[0];
        acc[i * 4 + 1] += lo[1];
        acc[i * 4 + 2] += hi[0];
        acc[i * 4 + 3] += hi[1];
    }
}

template <bool LAST>
__global__ __launch_bounds__(256) void k_agg(const unsigned char* __restrict__ hw8,
                                             const int* __restrict__ row_ptr,
                                             const int* __restrict__ colx,
                                             const float* __restrict__ inv_den,
                                             ushort* __restrict__ hb,
                                             const float* __restrict__ bias,
                                             float* __restrict__ g,
                                             int N, int ntiles) {
    int tid = threadIdx.x;
    int f = tid & 15;
    int gbase = tid & 48;
    const unsigned char* hp = hw8 + (size_t)f * 16;

    float csum[16];
    if constexpr (LAST) {
#pragma unroll
        for (int k = 0; k < 16; k++) csum[k] = 0.f;
    }

    for (int tile = blockIdx.x; tile < ntiles; tile += gridDim.x) {
        int node = tile * 16 + (tid >> 4);
        if (node < N) {
            int s = row_ptr[node], e = row_ptr[node + 1];
            float acc[16] = {};
            for (int base = s; base < e; base += 16) {
                int rem = e - base;
                int cnt = rem > 16 ? 16 : rem;
                int cv = (f < cnt) ? colx[base + f] : 0;
                int t = 0;
                for (; t + 3 < cnt; t += 4) {
                    int c0 = __shfl(cv, gbase + t);
                    int c1 = __shfl(cv, gbase + t + 1);
                    int c2 = __shfl(cv, gbase + t + 2);
                    int c3 = __shfl(cv, gbase + t + 3);
                    uint4 v0 = *(const uint4*)&hp[(size_t)c0 * HDIM];
                    uint4 v1 = *(const uint4*)&hp[(size_t)c1 * HDIM];
                    uint4 v2 = *(const uint4*)&hp[(size_t)c2 * HDIM];
                    uint4 v3 = *(const uint4*)&hp[(size_t)c3 * HDIM];
                    acc_fp8x16(v0, acc);
                    acc_fp8x16(v1, acc);
                    acc_fp8x16(v2, acc);
                    acc_fp8x16(v3, acc);
                }
                for (; t < cnt; t++) {
                    int c0 = __shfl(cv, gbase + t);
                    uint4 v0 = *(const uint4*)&hp[(size_t)c0 * HDIM];
                    acc_fp8x16(v0, acc);
                }
            }

            float inv = inv_den[node];
            ushort* hrow = &hb[(size_t)node * HDIM + f * 16];
            bf16x8 h0 = *(const bf16x8*)&hrow[0];
            bf16x8 h1 = *(const bf16x8*)&hrow[8];
            float4 b0 = *(const float4*)&bias[f * 16 + 0];
            float4 b1 = *(const float4*)&bias[f * 16 + 4];
            float4 b2 = *(const float4*)&bias[f * 16 + 8];
            float4 b3 = *(const float4*)&bias[f * 16 + 12];
            float bl[16] = {b0.x, b0.y, b0.z, b0.w, b1.x, b1.y, b1.z, b1.w,
                            b2.x, b2.y, b2.z, b2.w, b3.x, b3.y, b3.z, b3.w};
            float v[16];
#pragma unroll
            for (int k = 0; k < 8; k++) {
                v[k] = fmaxf(acc[k] * inv + bf2f((ushort)h0[k]) + bl[k], 0.f);
                v[k + 8] = fmaxf(acc[k + 8] * inv + bf2f((ushort)h1[k]) + bl[k + 8], 0.f);
            }
            if constexpr (LAST) {
#pragma unroll
                for (int k = 0; k < 16; k++) csum[k] += v[k];
            } else {
                ushort o[16];
#pragma unroll
                for (int k = 0; k < 16; k++) o[k] = f2bf(v[k]);
                *(uint4*)&hrow[0] = *(uint4*)&o[0];
                *(uint4*)&hrow[8] = *(uint4*)&o[8];
            }
        }
    }

    if constexpr (LAST) {
        __shared__ float cols[256];
        cols[tid] = 0.f;
        __syncthreads();
#pragma unroll
        for (int k = 0; k < 16; k++) atomicAdd(&cols[f * 16 + k], csum[k]);
        __syncthreads();
        atomicAdd(&g[tid], cols[tid]);
    }
}

// ---------------------------------------------------------------------------
// Tiny MLP head (fp32)
// ---------------------------------------------------------------------------
__global__ __launch_bounds__(256) void k_mlp(const float* __restrict__ g, const float* __restrict__ w1,
                                             const float* __restrict__ b1, const float* __restrict__ w2,
                                             const float* __restrict__ b2, float* __restrict__ out, float invN) {
    __shared__ float gs[256];
    __shared__ float ts[256];
    int f = threadIdx.x;
    gs[f] = g[f] * invN;
    __syncthreads();
    float a = b1[f];
    for (int k = 0; k < 256; k++) a = fmaf(gs[k], w1[k * 256 + f], a);
    ts[f] = fmaxf(a, 0.f);
    __syncthreads();
    float o = b2[f];
    for (int k = 0; k < 256; k++) o = fmaf(ts[k], w2[k * 256 + f], o);
    out[f] = o;
}

// ---------------------------------------------------------------------------
extern "C" void kernel_launch(void* const* d_in, const int* in_sizes, int n_in,
                              void* d_out, int out_size, void* d_ws, size_t ws_size,
                              hipStream_t stream) {
    const float* x      = (const float*)d_in[0];
    const int*   src    = (const int*)d_in[1];
    const int*   dst    = (const int*)d_in[2];
    const float* w_node = (const float*)d_in[3];
    const float* b_node = (const float*)d_in[4];
    const float* w_gnn  = (const float*)d_in[5];
    const float* b_gnn  = (const float*)d_in[6];
    const float* w_p1   = (const float*)d_in[7];
    const float* b_p1   = (const float*)d_in[8];
    const float* w_p2   = (const float*)d_in[9];
    const float* b_p2   = (const float*)d_in[10];
    float* out = (float*)d_out;

    const int N = in_sizes[0] / DNODE;  // 100000
    const int E = in_sizes[1];          // 1600000

    // workspace layout (~98 MB)
    char* w = (char*)d_ws;
    ushort* hb     = (ushort*)w;            w += (size_t)N * HDIM * 2;
    unsigned char* hw8 = (unsigned char*)w; w += (size_t)N * HDIM;
    ushort* xb     = (ushort*)w;            w += (size_t)N * DNODE * 2;
    ushort* wnt    = (ushort*)w;            w += (size_t)HDIM * DNODE * 2;
    ushort* wct    = (ushort*)w;            w += (size_t)HDIM * DNODE * 2;
    ushort* wgt    = (ushort*)w;            w += (size_t)NLAYERS * HDIM * HDIM * 2;
    float* bc      = (float*)w;             w += 256 * 4;
    int*   deg     = (int*)w;               w += (size_t)N * 4;
    int*   row_ptr = (int*)w;               w += (size_t)(N + 1) * 4;
    int*   cursor  = (int*)w;               w += (size_t)N * 4;
    int*   colx    = (int*)w;               w += (size_t)E * 4;
    float* inv_den = (float*)w;             w += (size_t)N * 4;
    float* g       = (float*)w;             w += 256 * 4;
    int*   bsum    = (int*)w;               w += 256 * 4;
    (void)ws_size; (void)n_in; (void)out_size;

    hipMemsetAsync(deg, 0, (size_t)N * 4, stream);
    hipMemsetAsync(g, 0, 256 * 4, stream);

    // deg histogram + converts + combined weight (one launch)
    int degB = (E + 255) / 256;
    int n4 = N * DNODE / 4;
    int xcB = (n4 + 255) / 256;
    int wcB = DNODE / 16 + NLAYERS * (HDIM / 16);
    k_pre<<<degB + xcB + wcB + DNODE + 1, 256, 0, stream>>>(dst, deg, E, degB, x, xb, n4, xcB,
                                                            w_node, wnt, w_gnn, wgt, wcB,
                                                            wct, bc, b_node);

    // scan chain
    int nb = (N + 2047) / 2048;
    k_scan_partial<<<nb, 256, 0, stream>>>(deg, bsum, N);
    k_scan_bsum<<<1, 64, 0, stream>>>(bsum, nb);
    k_scan_final<<<nb, 256, 0, stream>>>(deg, bsum, row_ptr, cursor, inv_den, N, E);

    // CSR fill — XCD-partitioned for colx L2 residency
    int npp = (N + NPART - 1) / NPART;
    int nslices = 256;
    k_fill_part<<<NPART * nslices, 256, 0, stream>>>(src, dst, cursor, colx, E, npp, nslices);

    // fused node projection: hb = x@Wn + bn ; hw8 = fp8(x@Wc + bc)
    dim3 gg(HDIM / 64, (N + 63) / 64);
    k_proj<<<gg, 256, 0, stream>>>(xb, wnt, wct, b_node, bc, hb, hw8, N);

    // GNN layers: agg(hw8) fused with residual+bias+relu; gemm produces next hw8
    int ntiles = (N + 15) / 16;
    for (int l = 0; l < NLAYERS; l++) {
        const float* bg = b_gnn + (size_t)l * HDIM;
        if (l < NLAYERS - 1) {
            k_agg<false><<<ntiles, 256, 0, stream>>>(hw8, row_ptr, colx, inv_den, hb, bg, nullptr, N, ntiles);
            k_gemm_hw<<<gg, 256, 0, stream>>>(hb, wgt + (size_t)(l + 1) * HDIM * HDIM, hw8, N);
        } else {
            int lgrid = (ntiles + 1) / 2;
            k_agg<true><<<lgrid, 256, 0, stream>>>(hw8, row_ptr, colx, inv_den, hb, bg, g, N, ntiles);
        }
    }

    k_mlp<<<1, 256, 0, stream>>>(g, w_p1, b_p1, w_p2, b_p2, out, 1.0f / (float)N);
}

// Round 12
// 582.582 us; speedup vs baseline: 1.5556x; 1.0121x over previous
//
#include <hip/hip_runtime.h>
#include <hip/hip_bf16.h>
#include <cstdint>
#include <cstddef>

#define DNODE 64
#define HDIM 256
#define NLAYERS 3
#define NPART 8
#define CSH 13   // src-chunk shift: 8192 nodes/chunk -> 2MB of hw8 per chunk

typedef __attribute__((ext_vector_type(8))) short bf16x8;
typedef __attribute__((ext_vector_type(4))) float f32x4;

__device__ __forceinline__ ushort f2bf(float f) {
    __hip_bfloat16 b = __float2bfloat16(f);
    return *(ushort*)&b;
}
__device__ __forceinline__ float bf2f(ushort u) {
    return __uint_as_float((uint32_t)u << 16);
}
__device__ __forceinline__ unsigned char f2fp8(float f) {
    int p = __builtin_amdgcn_cvt_pk_fp8_f32(f, f, 0, false);
    return (unsigned char)(p & 0xFF);
}

// ---------------------------------------------------------------------------
// k_pre: (dst,chunk) histogram + x->bf16 + weight transposes + Wc/bc
// ---------------------------------------------------------------------------
__global__ __launch_bounds__(256) void k_pre(const int* __restrict__ esrc, const int* __restrict__ edst,
                                             int* __restrict__ deg2, int E, int degB, int nch,
                                             const float* __restrict__ x, ushort* __restrict__ xb, int n4, int xcB,
                                             const float* __restrict__ w_node, ushort* __restrict__ wnt,
                                             const float* __restrict__ w_gnn, ushort* __restrict__ wgt, int wcB,
                                             ushort* __restrict__ wct, float* __restrict__ bc,
                                             const float* __restrict__ b_node) {
    int b = blockIdx.x, tid = threadIdx.x;
    if (b < degB) {
        int e = b * 256 + tid;
        if (e < E) {
            int d = edst[e];
            int c = esrc[e] >> CSH;
            atomicAdd(&deg2[(size_t)d * nch + c], 1);
        }
    } else if (b < degB + xcB) {
        int i = (b - degB) * 256 + tid;
        if (i < n4) {
            float4 v = *(const float4*)&x[(size_t)i * 4];
            ushort4 o;
            o.x = f2bf(v.x); o.y = f2bf(v.y); o.z = f2bf(v.z); o.w = f2bf(v.w);
            *(ushort4*)&xb[(size_t)i * 4] = o;
        }
    } else if (b < degB + xcB + wcB) {
        int wb = b - degB - xcB;
        int n = tid;
        if (wb < DNODE / 16) {
            int k0 = wb * 16;
#pragma unroll
            for (int i = 0; i < 16; i++)
                wnt[(size_t)n * DNODE + k0 + i] = f2bf(w_node[(size_t)(k0 + i) * HDIM + n]);
        } else {
            wb -= DNODE / 16;
            int l = wb >> 4, k0 = (wb & 15) * 16;
            const float* s = w_gnn + (size_t)l * HDIM * HDIM;
            ushort* d = wgt + (size_t)l * HDIM * HDIM;
#pragma unroll
            for (int i = 0; i < 16; i++)
                d[(size_t)n * HDIM + k0 + i] = f2bf(s[(size_t)(k0 + i) * HDIM + n]);
        }
    } else {
        int k = b - degB - xcB - wcB;   // 0..DNODE
        int n = tid;
        if (k < DNODE) {
            float s = 0.f;
            for (int j = 0; j < HDIM; j++) s = fmaf(w_node[(size_t)k * HDIM + j], w_gnn[(size_t)j * HDIM + n], s);
            wct[(size_t)n * DNODE + k] = f2bf(s);
        } else {
            float s = 0.f;
            for (int j = 0; j < HDIM; j++) s = fmaf(b_node[j], w_gnn[(size_t)j * HDIM + n], s);
            bc[n] = s;
        }
    }
}

// ---------------------------------------------------------------------------
// Scan chain over n2 = N*nch entries
// ---------------------------------------------------------------------------
__global__ __launch_bounds__(256) void k_scan_partial(const int* __restrict__ deg, int* __restrict__ bsum, int n) {
    __shared__ int sd[256];
    int tid = threadIdx.x;
    int base = blockIdx.x * 2048 + tid * 8;
    int s = 0;
#pragma unroll
    for (int j = 0; j < 8; j++) {
        int idx = base + j;
        if (idx < n) s += deg[idx];
    }
    sd[tid] = s;
    __syncthreads();
    for (int off = 128; off > 0; off >>= 1) {
        if (tid < off) sd[tid] += sd[tid + off];
        __syncthreads();
    }
    if (tid == 0) bsum[blockIdx.x] = sd[0];
}

// parallel exclusive scan of bsum (nb <= 1024), single block of 256 threads
__global__ __launch_bounds__(256) void k_scan_bsum(int* __restrict__ bsum, int nb) {
    __shared__ int ts[256];
    int tid = threadIdx.x;
    int v[4], loc[4];
    int s = 0;
#pragma unroll
    for (int j = 0; j < 4; j++) {
        int idx = tid * 4 + j;
        v[j] = (idx < nb) ? bsum[idx] : 0;
        loc[j] = s;
        s += v[j];
    }
    ts[tid] = s;
    __syncthreads();
    for (int off = 1; off < 256; off <<= 1) {
        int t = (tid >= off) ? ts[tid - off] : 0;
        __syncthreads();
        ts[tid] += t;
        __syncthreads();
    }
    int off0 = tid ? ts[tid - 1] : 0;
#pragma unroll
    for (int j = 0; j < 4; j++) {
        int idx = tid * 4 + j;
        if (idx < nb) bsum[idx] = off0 + loc[j];
    }
}

__global__ __launch_bounds__(256) void k_scan_final(const int* __restrict__ deg, const int* __restrict__ bsum,
                                                    int* __restrict__ rp2, int* __restrict__ cursor2,
                                                    int n, int Etot) {
    __shared__ int tsum[256];
    int tid = threadIdx.x;
    int base = blockIdx.x * 2048 + tid * 8;
    int loc[8], dv[8];
    int s = 0;
#pragma unroll
    for (int j = 0; j < 8; j++) {
        int idx = base + j;
        int v = (idx < n) ? deg[idx] : 0;
        dv[j] = v;
        loc[j] = s;
        s += v;
    }
    (void)dv;
    tsum[tid] = s;
    __syncthreads();
    for (int off = 1; off < 256; off <<= 1) {
        int t = (tid >= off) ? tsum[tid - off] : 0;
        __syncthreads();
        tsum[tid] += t;
        __syncthreads();
    }
    int off0 = bsum[blockIdx.x] + (tid ? tsum[tid - 1] : 0);
#pragma unroll
    for (int j = 0; j < 8; j++) {
        int idx = base + j;
        if (idx < n) {
            int rp = off0 + loc[j];
            rp2[idx] = rp;
            cursor2[idx] = rp;
        }
    }
    if (blockIdx.x == 0 && tid == 0) rp2[n] = Etot;
}

// ---------------------------------------------------------------------------
// k_fill_part: XCD-partitioned CSR fill with (dst,chunk) buckets -> each
// node's neighbor list is chunk-sorted (src-locality for the gather).
// ---------------------------------------------------------------------------
__global__ __launch_bounds__(256) void k_fill_part(const int* __restrict__ esrc, const int* __restrict__ edst,
                                                   int* __restrict__ cursor2, int* __restrict__ colx,
                                                   int E, int npp, int nslices, int nch) {
    int part = blockIdx.x & (NPART - 1);
    int slice = blockIdx.x / NPART;
    int lo = part * npp;
    int hi = lo + npp;
    int stride = nslices * 256;
    for (int e = slice * 256 + (int)threadIdx.x; e < E; e += stride) {
        int d = edst[e];
        if (d >= lo && d < hi) {
            int s = esrc[e];
            int c = s >> CSH;
            int p = atomicAdd(&cursor2[(size_t)d * nch + c], 1);
            colx[p] = s;
        }
    }
}

// ---------------------------------------------------------------------------
// k_proj: fused node projection (round-10 proven). hb = x@Wn + bn (bf16),
// hw8 = fp8(x@Wc + bc).
// ---------------------------------------------------------------------------
__global__ __launch_bounds__(256) void k_proj(const ushort* __restrict__ xb,
                                              const ushort* __restrict__ wnt,
                                              const ushort* __restrict__ wct,
                                              const float* __restrict__ bn,
                                              const float* __restrict__ bc,
                                              ushort* __restrict__ hb,
                                              unsigned char* __restrict__ hw8,
                                              int M) {
    __shared__ ushort As[64][40];
    __shared__ ushort Bs[64][40];
    __shared__ ushort Cs[64][40];
    int tid = threadIdx.x;
    int w = tid >> 6, l = tid & 63;
    int row0 = blockIdx.y * 64, col0 = blockIdx.x * 64;
    int sr = tid >> 2, sc = (tid & 3) * 8;
    int wm = (w >> 1) * 32, wn_ = (w & 1) * 32;
    int fr = l & 15, fk = (l >> 4) * 8;
    f32x4 acch[2][2] = {};
    f32x4 accw[2][2] = {};

    for (int k0 = 0; k0 < DNODE; k0 += 32) {
        bf16x8 av = {0, 0, 0, 0, 0, 0, 0, 0};
        int gr = row0 + sr;
        if (gr < M) av = *(const bf16x8*)&xb[(size_t)gr * DNODE + k0 + sc];
        *(bf16x8*)&As[sr][sc] = av;
        *(bf16x8*)&Bs[sr][sc] = *(const bf16x8*)&wnt[(size_t)(col0 + sr) * DNODE + k0 + sc];
        *(bf16x8*)&Cs[sr][sc] = *(const bf16x8*)&wct[(size_t)(col0 + sr) * DNODE + k0 + sc];
        __syncthreads();
        bf16x8 af[2], bff[2], cf[2];
#pragma unroll
        for (int mi = 0; mi < 2; mi++) af[mi] = *(const bf16x8*)&As[wm + mi * 16 + fr][fk];
#pragma unroll
        for (int ni = 0; ni < 2; ni++) {
            bff[ni] = *(const bf16x8*)&Bs[wn_ + ni * 16 + fr][fk];
            cf[ni] = *(const bf16x8*)&Cs[wn_ + ni * 16 + fr][fk];
        }
#pragma unroll
        for (int mi = 0; mi < 2; mi++)
#pragma unroll
            for (int ni = 0; ni < 2; ni++) {
                acch[mi][ni] = __builtin_amdgcn_mfma_f32_16x16x32_bf16(af[mi], bff[ni], acch[mi][ni], 0, 0, 0);
                accw[mi][ni] = __builtin_amdgcn_mfma_f32_16x16x32_bf16(af[mi], cf[ni], accw[mi][ni], 0, 0, 0);
            }
        __syncthreads();
    }

#pragma unroll
    for (int ni = 0; ni < 2; ni++) {
        int gcol = col0 + wn_ + ni * 16 + fr;
        float bbh = bn[gcol];
        float bbw = bc[gcol];
#pragma unroll
        for (int mi = 0; mi < 2; mi++) {
#pragma unroll
            for (int j = 0; j < 4; j++) {
                int grow = row0 + wm + mi * 16 + (l >> 4) * 4 + j;
                if (grow >= M) continue;
                size_t idx = (size_t)grow * HDIM + gcol;
                hb[idx] = f2bf(acch[mi][ni][j] + bbh);
                hw8[idx] = f2fp8(accw[mi][ni][j] + bbw);
            }
        }
    }
}

// ---------------------------------------------------------------------------
// k_gemm_hw: hw8 = fp8(hb @ Wt^T). (round-10 proven)
// ---------------------------------------------------------------------------
__global__ __launch_bounds__(256) void k_gemm_hw(const ushort* __restrict__ A,
                                                 const ushort* __restrict__ Bt,
                                                 unsigned char* __restrict__ hw8,
                                                 int M) {
    __shared__ ushort As[64][40];
    __shared__ ushort Bs[64][40];
    int tid = threadIdx.x;
    int w = tid >> 6, l = tid & 63;
    int row0 = blockIdx.y * 64, col0 = blockIdx.x * 64;
    int sr = tid >> 2, sc = (tid & 3) * 8;
    int wm = (w >> 1) * 32, wn = (w & 1) * 32;
    int fr = l & 15, fk = (l >> 4) * 8;
    f32x4 acc[2][2] = {};

    for (int k0 = 0; k0 < HDIM; k0 += 32) {
        bf16x8 av = {0, 0, 0, 0, 0, 0, 0, 0};
        int gr = row0 + sr;
        if (gr < M) av = *(const bf16x8*)&A[(size_t)gr * HDIM + k0 + sc];
        *(bf16x8*)&As[sr][sc] = av;
        *(bf16x8*)&Bs[sr][sc] = *(const bf16x8*)&Bt[(size_t)(col0 + sr) * HDIM + k0 + sc];
        __syncthreads();
        bf16x8 af[2], bf[2];
#pragma unroll
        for (int mi = 0; mi < 2; mi++) af[mi] = *(const bf16x8*)&As[wm + mi * 16 + fr][fk];
#pragma unroll
        for (int ni = 0; ni < 2; ni++) bf[ni] = *(const bf16x8*)&Bs[wn + ni * 16 + fr][fk];
#pragma unroll
        for (int mi = 0; mi < 2; mi++)
#pragma unroll
            for (int ni = 0; ni < 2; ni++)
                acc[mi][ni] = __builtin_amdgcn_mfma_f32_16x16x32_bf16(af[mi], bf[ni], acc[mi][ni], 0, 0, 0);
        __syncthreads();
    }

#pragma unroll
    for (int ni = 0; ni < 2; ni++) {
        int gcol = col0 + wn + ni * 16 + fr;
#pragma unroll
        for (int mi = 0; mi < 2; mi++) {
#pragma unroll
            for (int j = 0; j < 4; j++) {
                int grow = row0 + wm + mi * 16 + (l >> 4) * 4 + j;
                if (grow >= M) continue;
                hw8[(size_t)grow * HDIM + gcol] = f2fp8(acc[mi][ni][j]);
            }
        }
    }
}

// ---------------------------------------------------------------------------
// k_agg: SLIM gather-mean (round-5 body, VGPR-minimal). msgb = mean bf16.
// inv computed from (e - s); chunk-sorted colx gives L2 locality.
// ---------------------------------------------------------------------------
__device__ __forceinline__ void acc_fp8x16(uint4 v, float* acc) {
    uint32_t d[4] = {v.x, v.y, v.z, v.w};
#pragma unroll
    for (int i = 0; i < 4; i++) {
        auto lo = __builtin_amdgcn_cvt_pk_f32_fp8(d[i], false);
        auto hi = __builtin_amdgcn_cvt_pk_f32_fp8(d[i], true);
        acc[i * 4 + 0] += lo[0];
        acc[i * 4 + 1] += lo[1];
        acc[i * 4 + 2] += hi[0];
        acc[i * 4 + 3] += hi[1];
    }
}

__global__ __launch_bounds__(256) void k_agg(const unsigned char* __restrict__ hw8,
                                             const int* __restrict__ rp2,
                                             const int* __restrict__ colx,
                                             ushort* __restrict__ msgb, int N, int nch) {
    int tid = threadIdx.x;
    int node = blockIdx.x * 16 + (tid >> 4);
    if (node >= N) return;
    int f = tid & 15;
    int gbase = tid & 48;
    const unsigned char* hp = hw8 + (size_t)f * 16;

    int s = rp2[(size_t)node * nch];
    int e = rp2[(size_t)node * nch + nch];
    float acc[16] = {};

    for (int base = s; base < e; base += 16) {
        int rem = e - base;
        int cnt = rem > 16 ? 16 : rem;
        int cv = (f < cnt) ? colx[base + f] : 0;
        int t = 0;
        for (; t + 3 < cnt; t += 4) {
            int c0 = __shfl(cv, gbase + t);
            int c1 = __shfl(cv, gbase + t + 1);
            int c2 = __shfl(cv, gbase + t + 2);
            int c3 = __shfl(cv, gbase + t + 3);
            uint4 v0 = *(const uint4*)&hp[(size_t)c0 * HDIM];
            uint4 v1 = *(const uint4*)&hp[(size_t)c1 * HDIM];
            uint4 v2 = *(const uint4*)&hp[(size_t)c2 * HDIM];
            uint4 v3 = *(const uint4*)&hp[(size_t)c3 * HDIM];
            acc_fp8x16(v0, acc);
            acc_fp8x16(v1, acc);
            acc_fp8x16(v2, acc);
            acc_fp8x16(v3, acc);
        }
        for (; t < cnt; t++) {
            int c0 = __shfl(cv, gbase + t);
            uint4 v0 = *(const uint4*)&hp[(size_t)c0 * HDIM];
            acc_fp8x16(v0, acc);
        }
    }

    int d = e - s;
    float inv = 1.0f / (float)(d > 0 ? d : 1);
    ushort o[16];
#pragma unroll
    for (int k = 0; k < 16; k++) o[k] = f2bf(acc[k] * inv);
    ushort* mp = &msgb[(size_t)node * HDIM + f * 16];
    *(uint4*)&mp[0] = *(uint4*)&o[0];
    *(uint4*)&mp[8] = *(uint4*)&o[8];
}

// ---------------------------------------------------------------------------
// k_resid: hb = relu(hb + msgb + bias)  (streaming elementwise, bf16x8)
// ---------------------------------------------------------------------------
__global__ __launch_bounds__(256) void k_resid(ushort* __restrict__ hb, const ushort* __restrict__ msgb,
                                               const float* __restrict__ bias, int total8) {
    int stride = gridDim.x * 256;
    for (int i = blockIdx.x * 256 + (int)threadIdx.x; i < total8; i += stride) {
        int col0 = (i & 31) * 8;
        size_t off = (size_t)i * 8;
        bf16x8 h = *(const bf16x8*)&hb[off];
        bf16x8 m = *(const bf16x8*)&msgb[off];
        float4 b0 = *(const float4*)&bias[col0];
        float4 b1 = *(const float4*)&bias[col0 + 4];
        float bl[8] = {b0.x, b0.y, b0.z, b0.w, b1.x, b1.y, b1.z, b1.w};
        ushort o[8];
#pragma unroll
        for (int k = 0; k < 8; k++)
            o[k] = f2bf(fmaxf(bf2f((ushort)h[k]) + bf2f((ushort)m[k]) + bl[k], 0.f));
        *(uint4*)&hb[off] = *(uint4*)o;
    }
}

// ---------------------------------------------------------------------------
// k_colsum_res: g += colsum(relu(hb + msgb + bias))  (streaming, LDS reduce)
// ---------------------------------------------------------------------------
__global__ __launch_bounds__(256) void k_colsum_res(const ushort* __restrict__ hb, const ushort* __restrict__ msgb,
                                                    const float* __restrict__ bias, float* __restrict__ g, int N) {
    __shared__ float cols[256];
    int tid = threadIdx.x;
    int f8 = tid & 31, r = tid >> 5;
    int col0 = f8 * 8;
    float4 b0 = *(const float4*)&bias[col0];
    float4 b1 = *(const float4*)&bias[col0 + 4];
    float bl[8] = {b0.x, b0.y, b0.z, b0.w, b1.x, b1.y, b1.z, b1.w};
    float acc[8] = {};
    for (int row = blockIdx.x * 8 + r; row < N; row += gridDim.x * 8) {
        size_t off = (size_t)row * HDIM + col0;
        bf16x8 h = *(const bf16x8*)&hb[off];
        bf16x8 m = *(const bf16x8*)&msgb[off];
#pragma unroll
        for (int k = 0; k < 8; k++)
            acc[k] += fmaxf(bf2f((ushort)h[k]) + bf2f((ushort)m[k]) + bl[k], 0.f);
    }
    cols[tid] = 0.f;
    __syncthreads();
#pragma unroll
    for (int k = 0; k < 8; k++) atomicAdd(&cols[col0 + k], acc[k]);
    __syncthreads();
    atomicAdd(&g[tid], cols[tid]);
}

// ---------------------------------------------------------------------------
// Tiny MLP head (fp32)
// ---------------------------------------------------------------------------
__global__ __launch_bounds__(256) void k_mlp(const float* __restrict__ g, const float* __restrict__ w1,
                                             const float* __restrict__ b1, const float* __restrict__ w2,
                                             const float* __restrict__ b2, float* __restrict__ out, float invN) {
    __shared__ float gs[256];
    __shared__ float ts[256];
    int f = threadIdx.x;
    gs[f] = g[f] * invN;
    __syncthreads();
    float a = b1[f];
    for (int k = 0; k < 256; k++) a = fmaf(gs[k], w1[k * 256 + f], a);
    ts[f] = fmaxf(a, 0.f);
    __syncthreads();
    float o = b2[f];
    for (int k = 0; k < 256; k++) o = fmaf(ts[k], w2[k * 256 + f], o);
    out[f] = o;
}

// ---------------------------------------------------------------------------
extern "C" void kernel_launch(void* const* d_in, const int* in_sizes, int n_in,
                              void* d_out, int out_size, void* d_ws, size_t ws_size,
                              hipStream_t stream) {
    const float* x      = (const float*)d_in[0];
    const int*   src    = (const int*)d_in[1];
    const int*   dst    = (const int*)d_in[2];
    const float* w_node = (const float*)d_in[3];
    const float* b_node = (const float*)d_in[4];
    const float* w_gnn  = (const float*)d_in[5];
    const float* b_gnn  = (const float*)d_in[6];
    const float* w_p1   = (const float*)d_in[7];
    const float* b_p1   = (const float*)d_in[8];
    const float* w_p2   = (const float*)d_in[9];
    const float* b_p2   = (const float*)d_in[10];
    float* out = (float*)d_out;

    const int N = in_sizes[0] / DNODE;  // 100000
    const int E = in_sizes[1];          // 1600000
    const int nch = (N + (1 << CSH) - 1) >> CSH;  // 13
    const int n2 = N * nch;

    // workspace layout (~205 MB)
    char* w = (char*)d_ws;
    ushort* hb     = (ushort*)w;            w += (size_t)N * HDIM * 2;
    ushort* msgb   = (ushort*)w;            w += (size_t)N * HDIM * 2;
    unsigned char* hw8 = (unsigned char*)w; w += (size_t)N * HDIM;
    ushort* xb     = (ushort*)w;            w += (size_t)N * DNODE * 2;
    ushort* wnt    = (ushort*)w;            w += (size_t)HDIM * DNODE * 2;
    ushort* wct    = (ushort*)w;            w += (size_t)HDIM * DNODE * 2;
    ushort* wgt    = (ushort*)w;            w += (size_t)NLAYERS * HDIM * HDIM * 2;
    float* bc      = (float*)w;             w += 256 * 4;
    int*   deg2    = (int*)w;               w += (size_t)n2 * 4;
    int*   rp2     = (int*)w;               w += (size_t)(n2 + 1) * 4;
    int*   cursor2 = (int*)w;               w += (size_t)n2 * 4;
    int*   colx    = (int*)w;               w += (size_t)E * 4;
    float* g       = (float*)w;             w += 256 * 4;
    int*   bsum    = (int*)w;               w += 1024 * 4;
    (void)ws_size; (void)n_in; (void)out_size;

    hipMemsetAsync(deg2, 0, (size_t)n2 * 4, stream);
    hipMemsetAsync(g, 0, 256 * 4, stream);

    // (dst,chunk) histogram + converts + combined weight (one launch)
    int degB = (E + 255) / 256;
    int n4 = N * DNODE / 4;
    int xcB = (n4 + 255) / 256;
    int wcB = DNODE / 16 + NLAYERS * (HDIM / 16);
    k_pre<<<degB + xcB + wcB + DNODE + 1, 256, 0, stream>>>(src, dst, deg2, E, degB, nch,
                                                            x, xb, n4, xcB,
                                                            w_node, wnt, w_gnn, wgt, wcB,
                                                            wct, bc, b_node);

    // scan chain over n2 entries
    int nb2 = (n2 + 2047) / 2048;   // 635 <= 1024
    k_scan_partial<<<nb2, 256, 0, stream>>>(deg2, bsum, n2);
    k_scan_bsum<<<1, 256, 0, stream>>>(bsum, nb2);
    k_scan_final<<<nb2, 256, 0, stream>>>(deg2, bsum, rp2, cursor2, n2, E);

    // CSR fill — XCD-partitioned, chunk-sorted adjacency
    int npp = (N + NPART - 1) / NPART;
    int nslices = 256;
    k_fill_part<<<NPART * nslices, 256, 0, stream>>>(src, dst, cursor2, colx, E, npp, nslices, nch);

    // fused node projection: hb = x@Wn + bn ; hw8 = fp8(x@Wc + bc)
    dim3 gg(HDIM / 64, (N + 63) / 64);
    k_proj<<<gg, 256, 0, stream>>>(xb, wnt, wct, b_node, bc, hb, hw8, N);

    // GNN layers
    int nagg = (N + 15) / 16;
    int total8 = N * (HDIM / 8);
    for (int l = 0; l < NLAYERS; l++) {
        const float* bg = b_gnn + (size_t)l * HDIM;
        k_agg<<<nagg, 256, 0, stream>>>(hw8, rp2, colx, msgb, N, nch);
        if (l < NLAYERS - 1) {
            k_resid<<<2048, 256, 0, stream>>>(hb, msgb, bg, total8);
            k_gemm_hw<<<gg, 256, 0, stream>>>(hb, wgt + (size_t)(l + 1) * HDIM * HDIM, hw8, N);
        } else {
            k_colsum_res<<<1024, 256, 0, stream>>>(hb, msgb, bg, g, N);
        }
    }

    k_mlp<<<1, 256, 0, stream>>>(g, w_p1, b_p1, w_p2, b_p2, out, 1.0f / (float)N);
}